// Round 1
// baseline (421.086 us; speedup 1.0000x reference)
//
#include <hip/hip_runtime.h>

#define SEQ   8192
#define DDIM  512
#define NCH   128

typedef _Float16 half8 __attribute__((ext_vector_type(8)));
typedef _Float16 half4 __attribute__((ext_vector_type(4)));
typedef float    f32x4 __attribute__((ext_vector_type(4)));

#define MFMA(A, B, Cc) __builtin_amdgcn_mfma_f32_16x16x32_f16((A), (B), (Cc), 0, 0, 0)

__device__ __forceinline__ int swz(int row, int colByte) {
  return colByte ^ ((row & 7) << 4);
}

// load 8 consecutive fp32 from a W row, convert to fp16 MFMA fragment
__device__ __forceinline__ half8 ldw_frag(const float* __restrict__ W, int row, int e0) {
  const float4* p = reinterpret_cast<const float4*>(W + ((size_t)row << 9) + e0);
  float4 f0 = p[0];
  float4 f1 = p[1];
  half8 v;
  v[0] = (_Float16)f0.x; v[1] = (_Float16)f0.y; v[2] = (_Float16)f0.z; v[3] = (_Float16)f0.w;
  v[4] = (_Float16)f1.x; v[5] = (_Float16)f1.y; v[6] = (_Float16)f1.z; v[7] = (_Float16)f1.w;
  return v;
}

// swizzled LDS fragment read: row-major [row][col] fp16, strideBytes per row
__device__ __forceinline__ half8 ldl_frag(const unsigned short* buf, int row, int col, int strideBytes) {
  int byte = row * strideBytes + swz(row, col << 1);
  return *reinterpret_cast<const half8*>(reinterpret_cast<const char*>(buf) + byte);
}

__global__ __launch_bounds__(256, 1)
void ep_fused(const float* __restrict__ x, const float* __restrict__ Wq,
              const float* __restrict__ Wk, const float* __restrict__ Wv,
              float* __restrict__ out)
{
  // 160 KiB total (gfx950 max workgroup LDS)
  __shared__ unsigned short xs[128 * 512];  // x_ctx fp16, stride 1024B, swizzled
  __shared__ unsigned short kv[64 * 128];   // phase S: k[j<128][d<64] s=128B ; phase PV: v[d<64][j<128] s=256B
  __shared__ unsigned short pq[64 * 128];   // phase S: q[q<64][d<64] s=128B ; phase PV: p[q<64][j<128] s=256B

  const int bc   = blockIdx.x;
  const int b    = bc >> 7;
  const int c    = bc & (NCH - 1);
  const int tid  = threadIdx.x;
  const int lane = tid & 63;
  const int w    = tid >> 6;   // wave id 0..3
  const int l15  = lane & 15;
  const int h    = lane >> 4;

  // ---------------- stage x_ctx = [prev chunk ; cur chunk] -> LDS fp16 ----------------
  const float* xb = x + (size_t)b * (SEQ * DDIM);
  #pragma unroll
  for (int i = 0; i < 32; ++i) {
    int unit = tid + (i << 8);      // 0..8191, each = 8 floats
    int row  = unit >> 6;           // 0..127  (0..63 prev, 64..127 cur)
    int e0   = (unit & 63) << 3;    // 0..504
    half8 v;
    if (c == 0 && row < 64) {
      #pragma unroll
      for (int t = 0; t < 8; ++t) v[t] = (_Float16)0.0f;
    } else {
      int s = c * 64 - 64 + row;
      const float4* p = reinterpret_cast<const float4*>(xb + (size_t)s * DDIM + e0);
      float4 f0 = p[0], f1 = p[1];
      v[0] = (_Float16)f0.x; v[1] = (_Float16)f0.y; v[2] = (_Float16)f0.z; v[3] = (_Float16)f0.w;
      v[4] = (_Float16)f1.x; v[5] = (_Float16)f1.y; v[6] = (_Float16)f1.z; v[7] = (_Float16)f1.w;
    }
    int byte = (row << 10) + swz(row, e0 << 1);
    *reinterpret_cast<half8*>(reinterpret_cast<char*>(xs) + byte) = v;
  }
  __syncthreads();

  // ---------------- S = (x_cur Wq^T)(x_ctx Wk^T)^T, accumulated over 8 d-tiles ----------------
  f32x4 Sacc[8] = {};
  const int d0 = (w << 4) + (h << 2);   // C-frag row base (d) for W-as-A GEMMs

  for (int dt = 0; dt < 8; ++dt) {
    const int drow = (dt << 6) + (w << 4) + l15;

    // q^T tile: C[d][q] = sum_e Wq[d][e] * x_cur[q][e]
    f32x4 qa[4] = {};
    for (int ks = 0; ks < 16; ++ks) {
      half8 a = ldw_frag(Wq, drow, (ks << 5) + (h << 3));
      #pragma unroll
      for (int nt = 0; nt < 4; ++nt) {
        half8 bf = ldl_frag(xs, 64 + (nt << 4) + l15, (ks << 5) + (h << 3), 1024);
        qa[nt] = MFMA(a, bf, qa[nt]);
      }
    }
    #pragma unroll
    for (int nt = 0; nt < 4; ++nt) {  // write q[q][d] (stride 128B)
      int q = (nt << 4) + l15;
      half4 hv;
      hv[0] = (_Float16)qa[nt][0]; hv[1] = (_Float16)qa[nt][1];
      hv[2] = (_Float16)qa[nt][2]; hv[3] = (_Float16)qa[nt][3];
      *reinterpret_cast<half4*>(reinterpret_cast<char*>(pq) + q * 128 + swz(q, d0 << 1)) = hv;
    }

    // k^T tile: C[d][j] = sum_e Wk[d][e] * x_ctx[j][e]
    f32x4 ka[8] = {};
    for (int ks = 0; ks < 16; ++ks) {
      half8 a = ldw_frag(Wk, drow, (ks << 5) + (h << 3));
      #pragma unroll
      for (int nt = 0; nt < 8; ++nt) {
        half8 bf = ldl_frag(xs, (nt << 4) + l15, (ks << 5) + (h << 3), 1024);
        ka[nt] = MFMA(a, bf, ka[nt]);
      }
    }
    #pragma unroll
    for (int nt = 0; nt < 8; ++nt) {  // write k[j][d] (stride 128B)
      int j = (nt << 4) + l15;
      half4 hv;
      hv[0] = (_Float16)ka[nt][0]; hv[1] = (_Float16)ka[nt][1];
      hv[2] = (_Float16)ka[nt][2]; hv[3] = (_Float16)ka[nt][3];
      *reinterpret_cast<half4*>(reinterpret_cast<char*>(kv) + j * 128 + swz(j, d0 << 1)) = hv;
    }
    __syncthreads();

    // S += q_dt @ k_dt^T   (wave w owns q rows 16w..16w+15, all 128 j)
    #pragma unroll
    for (int ksd = 0; ksd < 2; ++ksd) {
      half8 a = ldl_frag(pq, (w << 4) + l15, (ksd << 5) + (h << 3), 128);
      #pragma unroll
      for (int nt = 0; nt < 8; ++nt) {
        half8 bf = ldl_frag(kv, (nt << 4) + l15, (ksd << 5) + (h << 3), 128);
        Sacc[nt] = MFMA(a, bf, Sacc[nt]);
      }
    }
    __syncthreads();
  }

  // ---------------- masked softmax (rows live in 16-lane groups) ----------------
  const float scale = 0.044194173824159216f;  // 1/sqrt(512)
  #pragma unroll
  for (int nt = 0; nt < 8; ++nt) {
    int j = (nt << 4) + l15;
    #pragma unroll
    for (int r = 0; r < 4; ++r) {
      int qrow = (w << 4) + (h << 2) + r;
      bool valid = (j < 64 + qrow) && ((c > 0) || (j >= 64));
      Sacc[nt][r] = valid ? Sacc[nt][r] * scale : -1e30f;
    }
  }
  float inv[4];
  #pragma unroll
  for (int r = 0; r < 4; ++r) {
    float mx = -1e30f;
    #pragma unroll
    for (int nt = 0; nt < 8; ++nt) mx = fmaxf(mx, Sacc[nt][r]);
    mx = fmaxf(mx, __shfl_xor(mx, 1));
    mx = fmaxf(mx, __shfl_xor(mx, 2));
    mx = fmaxf(mx, __shfl_xor(mx, 4));
    mx = fmaxf(mx, __shfl_xor(mx, 8));
    float sum = 0.f;
    #pragma unroll
    for (int nt = 0; nt < 8; ++nt) {
      float sv = Sacc[nt][r];
      float pe = (sv > -1e29f) ? __expf(sv - mx) : 0.f;
      Sacc[nt][r] = pe;
      sum += pe;
    }
    sum += __shfl_xor(sum, 1);
    sum += __shfl_xor(sum, 2);
    sum += __shfl_xor(sum, 4);
    sum += __shfl_xor(sum, 8);
    inv[r] = (sum > 0.f) ? (1.0f / sum) : 0.f;   // fully-masked row -> p = 0
  }
  #pragma unroll
  for (int nt = 0; nt < 8; ++nt) {  // p[q][j] fp16, stride 256B
    int j = (nt << 4) + l15;
    #pragma unroll
    for (int r = 0; r < 4; ++r) {
      int qrow = (w << 4) + (h << 2) + r;
      _Float16 ph = (_Float16)(Sacc[nt][r] * inv[r]);
      *reinterpret_cast<_Float16*>(reinterpret_cast<char*>(pq) + qrow * 256 + swz(qrow, j << 1)) = ph;
    }
  }
  __syncthreads();

  // ---------------- out = p @ (x_ctx Wv^T), per 64-wide d-tile ----------------
  for (int dt = 0; dt < 8; ++dt) {
    const int dcol = (dt << 6) + (w << 4) + l15;   // wave w owns d-cols 16w..16w+15 of this tile

    // v tile: C[j][d] = sum_e x_ctx[j][e] * Wv[d][e]
    f32x4 va[8] = {};
    for (int ks = 0; ks < 16; ++ks) {
      half8 bf = ldw_frag(Wv, dcol, (ks << 5) + (h << 3));
      #pragma unroll
      for (int mt = 0; mt < 8; ++mt) {
        half8 a = ldl_frag(xs, (mt << 4) + l15, (ks << 5) + (h << 3), 1024);
        va[mt] = MFMA(a, bf, va[mt]);
      }
    }
    {
      int dl = (w << 4) + l15;
      #pragma unroll
      for (int mt = 0; mt < 8; ++mt) {  // write v[d][j] (stride 256B)
        int j0 = (mt << 4) + (h << 2);
        half4 hv;
        hv[0] = (_Float16)va[mt][0]; hv[1] = (_Float16)va[mt][1];
        hv[2] = (_Float16)va[mt][2]; hv[3] = (_Float16)va[mt][3];
        *reinterpret_cast<half4*>(reinterpret_cast<char*>(kv) + dl * 256 + swz(dl, j0 << 1)) = hv;
      }
    }
    __syncthreads();

    // out tile: C[q][d] = sum_j p[q][j] * v[d][j]
    f32x4 oa[4] = {};
    #pragma unroll
    for (int ks = 0; ks < 4; ++ks) {
      half8 a = ldl_frag(pq, (w << 4) + l15, (ks << 5) + (h << 3), 256);
      #pragma unroll
      for (int nt = 0; nt < 4; ++nt) {
        half8 bf = ldl_frag(kv, (nt << 4) + l15, (ks << 5) + (h << 3), 256);
        oa[nt] = MFMA(a, bf, oa[nt]);
      }
    }
    #pragma unroll
    for (int nt = 0; nt < 4; ++nt) {
      int d = (dt << 6) + (nt << 4) + l15;
      #pragma unroll
      for (int r = 0; r < 4; ++r) {
        int qrow = (w << 4) + (h << 2) + r;
        out[((size_t)(b * SEQ + (c << 6) + qrow) << 9) + d] = oa[nt][r];
      }
    }
    __syncthreads();
  }
}

extern "C" void kernel_launch(void* const* d_in, const int* in_sizes, int n_in,
                              void* d_out, int out_size, void* d_ws, size_t ws_size,
                              hipStream_t stream) {
  const float* x  = (const float*)d_in[0];
  const float* Wq = (const float*)d_in[1];
  const float* Wk = (const float*)d_in[2];
  const float* Wv = (const float*)d_in[3];
  float* out = (float*)d_out;
  (void)in_sizes; (void)n_in; (void)d_ws; (void)ws_size; (void)out_size;

  dim3 grid(4 * NCH);   // b * 128 + chunk
  dim3 block(256);
  hipLaunchKernelGGL(ep_fused, grid, block, 0, stream, x, Wq, Wk, Wv, out);
}

// Round 2
// 254.172 us; speedup vs baseline: 1.6567x; 1.6567x over previous
//
#include <hip/hip_runtime.h>

#define SEQ   8192
#define DDIM  512
#define NCH   128
#define SCALE 0.044194173824159216f   // 1/sqrt(512)

typedef _Float16 half8 __attribute__((ext_vector_type(8)));
typedef _Float16 half4 __attribute__((ext_vector_type(4)));
typedef float    f32x4 __attribute__((ext_vector_type(4)));

#define MFMA(A, B, Cc) __builtin_amdgcn_mfma_f32_16x16x32_f16((A), (B), (Cc), 0, 0, 0)

// ---------------- ws layout (bytes) ----------------
#define X16_OFF 0ull
#define Q16_OFF 33554432ull
#define K16_OFF 67108864ull
#define VT_OFF  100663296ull
#define W16_OFF 134217728ull     // Wq16, Wk16, Wv16 (512KB each)
#define WS_NEED 135790592ull

// ================= K0: fp32 -> fp16 convert (x, and W with scale folded into Wq) =================
__global__ __launch_bounds__(256)
void k0_cvt(const float* __restrict__ x, const float* __restrict__ Wq,
            const float* __restrict__ Wk, const float* __restrict__ Wv,
            _Float16* __restrict__ x16, _Float16* __restrict__ w16)
{
  const long long NX = 16777216LL;   // 4*8192*512
  long long base = ((long long)blockIdx.x * 256 + threadIdx.x) * 8;
  const float* src;
  _Float16* dst;
  float sc = 1.0f;
  if (base < NX) {
    src = x + base; dst = x16 + base;
  } else {
    long long o = base - NX;             // 0 .. 786431
    int ws = (int)(o >> 18);             // /262144
    long long oo = o & 262143LL;
    src = (ws == 0 ? Wq : (ws == 1 ? Wk : Wv)) + oo;
    dst = w16 + o;
    if (ws == 0) sc = SCALE;
  }
  const float4* p = (const float4*)src;
  float4 f0 = p[0], f1 = p[1];
  half8 v;
  v[0] = (_Float16)(f0.x * sc); v[1] = (_Float16)(f0.y * sc);
  v[2] = (_Float16)(f0.z * sc); v[3] = (_Float16)(f0.w * sc);
  v[4] = (_Float16)(f1.x * sc); v[5] = (_Float16)(f1.y * sc);
  v[6] = (_Float16)(f1.z * sc); v[7] = (_Float16)(f1.w * sc);
  *(half8*)dst = v;
}

// ================= K1: q = x Wq~^T, k = x Wk^T (row-major), vT = (x Wv^T)^T =================
// grid (256 s-tiles, 4 d-tiles, 3 weights), 256 threads, 4 waves in 2x2.
__global__ __launch_bounds__(256)
void k1_gemm(const _Float16* __restrict__ x16, const _Float16* __restrict__ w16,
             _Float16* __restrict__ q16, _Float16* __restrict__ k16,
             _Float16* __restrict__ vT)
{
  __shared__ unsigned short xs[2][8192];   // two 16KB buffers: [128 s][64 e] fp16, swizzled

  const int stile = blockIdx.x;
  const int dtile = blockIdx.y;
  const int wsel  = blockIdx.z;
  const int tid = threadIdx.x, lane = tid & 63, w = tid >> 6;
  const int l15 = lane & 15, h = lane >> 4;

  const _Float16* W = w16 + ((size_t)wsel << 18);
  const _Float16* xbase = x16 + (size_t)stile * 128 * 512;

  // staging: 1024 units of 16B; thread t owns units {t, 256+t, 512+t, 768+t}
  int srow[4], scb[4];
  #pragma unroll
  for (int i = 0; i < 4; ++i) { int u = (i << 8) + tid; srow[i] = u >> 3; scb[i] = (u & 7) << 4; }

  half8 st[4];
  auto issue = [&](int kk) {
    #pragma unroll
    for (int i = 0; i < 4; ++i)
      st[i] = *(const half8*)(xbase + (size_t)srow[i] * 512 + kk * 64 + (scb[i] >> 1));
  };
  auto stw = [&](int buf) {
    #pragma unroll
    for (int i = 0; i < 4; ++i) {
      int byte = srow[i] * 128 + (scb[i] ^ ((srow[i] & 7) << 4));
      *(half8*)((char*)xs[buf] + byte) = st[i];
    }
  };
  auto lds_frag = [&](int buf, int row, int colh) -> half8 {
    int byte = row * 128 + (((colh) << 1) ^ ((row & 7) << 4));
    return *(const half8*)((const char*)xs[buf] + byte);
  };

  f32x4 acc[4][4] = {};
  const bool vpath = (wsel == 2);

  issue(0);
  int cur = 0;
  for (int kk = 0; kk < 8; ++kk) {
    stw(cur);
    __syncthreads();
    if (kk < 7) issue(kk + 1);

    if (!vpath) {
      // C[s][d]: A = x (LDS), B = W (global, L2-resident)
      const _Float16* Wt = W + (size_t)(dtile * 128 + (w & 1) * 64) * 512 + kk * 64;
      #pragma unroll
      for (int ks = 0; ks < 2; ++ks) {
        half8 a[4], bf[4];
        #pragma unroll
        for (int mr = 0; mr < 4; ++mr)
          a[mr] = lds_frag(cur, (w >> 1) * 64 + mr * 16 + l15, ks * 32 + h * 8);
        #pragma unroll
        for (int nr = 0; nr < 4; ++nr)
          bf[nr] = *(const half8*)(Wt + (size_t)(nr * 16 + l15) * 512 + ks * 32 + h * 8);
        #pragma unroll
        for (int mr = 0; mr < 4; ++mr)
          #pragma unroll
          for (int nr = 0; nr < 4; ++nr)
            acc[mr][nr] = MFMA(a[mr], bf[nr], acc[mr][nr]);
      }
    } else {
      // C[d][s]: A = W (global), B = x (LDS)  -> writes vT directly
      const _Float16* Wt = W + (size_t)(dtile * 128 + (w >> 1) * 64) * 512 + kk * 64;
      #pragma unroll
      for (int ks = 0; ks < 2; ++ks) {
        half8 a[4], bf[4];
        #pragma unroll
        for (int mr = 0; mr < 4; ++mr)
          a[mr] = *(const half8*)(Wt + (size_t)(mr * 16 + l15) * 512 + ks * 32 + h * 8);
        #pragma unroll
        for (int nr = 0; nr < 4; ++nr)
          bf[nr] = lds_frag(cur, (w & 1) * 64 + nr * 16 + l15, ks * 32 + h * 8);
        #pragma unroll
        for (int mr = 0; mr < 4; ++mr)
          #pragma unroll
          for (int nr = 0; nr < 4; ++nr)
            acc[mr][nr] = MFMA(a[mr], bf[nr], acc[mr][nr]);
      }
    }
    __syncthreads();
    cur ^= 1;
  }

  if (!vpath) {
    _Float16* dst = (wsel == 0) ? q16 : k16;
    const int m0 = stile * 128 + (w >> 1) * 64;
    const int n0 = dtile * 128 + (w & 1) * 64;
    #pragma unroll
    for (int mr = 0; mr < 4; ++mr)
      #pragma unroll
      for (int nr = 0; nr < 4; ++nr)
        #pragma unroll
        for (int r = 0; r < 4; ++r)
          dst[(size_t)(m0 + mr * 16 + h * 4 + r) * 512 + n0 + nr * 16 + l15] =
              (_Float16)acc[mr][nr][r];
  } else {
    const int d0 = dtile * 128 + (w >> 1) * 64;
    const int sg = stile * 128 + (w & 1) * 64;
    const int b = sg >> 13, s0 = sg & 8191;
    _Float16* dst = vT + (size_t)b * 512 * 8192;
    #pragma unroll
    for (int mr = 0; mr < 4; ++mr)
      #pragma unroll
      for (int nr = 0; nr < 4; ++nr)
        #pragma unroll
        for (int r = 0; r < 4; ++r)
          dst[(size_t)(d0 + mr * 16 + h * 4 + r) * 8192 + s0 + nr * 16 + l15] =
              (_Float16)acc[mr][nr][r];
  }
}

// ================= K2: chunked attention, one wave per (b, c, 16 q-rows) =================
__global__ __launch_bounds__(64)
void k2_attn(const _Float16* __restrict__ q16, const _Float16* __restrict__ k16,
             const _Float16* __restrict__ vT, float* __restrict__ out)
{
  __shared__ unsigned short p_lds[16 * 128];   // 4KB, [16 q][128 j] fp16, swizzled, wave-local

  const int bx = blockIdx.x;
  const int b = bx >> 9, c = (bx >> 2) & 127, w = bx & 3;
  const int lane = threadIdx.x & 63, l15 = lane & 15, h = lane >> 4;

  const int jbase = c * 64 - 64;

  // ---- S = q~ @ k^T over K=512 ----
  const _Float16* qrow = q16 + (size_t)(b * 8192 + c * 64 + w * 16 + l15) * 512;
  const _Float16* kb   = k16 + (size_t)b * 8192 * 512;
  f32x4 S[8] = {};
  #pragma unroll 2
  for (int ks = 0; ks < 16; ++ks) {
    half8 a = *(const half8*)(qrow + ks * 32 + h * 8);
    #pragma unroll
    for (int jt = 0; jt < 8; ++jt) {
      int j = jbase + jt * 16 + l15;
      if (j < 0) j = 0;                    // c==0 only; masked below
      half8 bf = *(const half8*)(kb + (size_t)j * 512 + ks * 32 + h * 8);
      S[jt] = MFMA(a, bf, S[jt]);
    }
  }

  // ---- masked softmax (row q = h*4+r lives in 16-lane group) ----
  #pragma unroll
  for (int jt = 0; jt < 8; ++jt) {
    int j = jt * 16 + l15;
    #pragma unroll
    for (int r = 0; r < 4; ++r) {
      int ql = w * 16 + h * 4 + r;
      bool valid = (j < 64 + ql) && ((c > 0) || (j >= 64));
      S[jt][r] = valid ? S[jt][r] : -1e30f;
    }
  }
  #pragma unroll
  for (int r = 0; r < 4; ++r) {
    float mx = -1e30f;
    #pragma unroll
    for (int jt = 0; jt < 8; ++jt) mx = fmaxf(mx, S[jt][r]);
    mx = fmaxf(mx, __shfl_xor(mx, 1));
    mx = fmaxf(mx, __shfl_xor(mx, 2));
    mx = fmaxf(mx, __shfl_xor(mx, 4));
    mx = fmaxf(mx, __shfl_xor(mx, 8));
    float sum = 0.f;
    #pragma unroll
    for (int jt = 0; jt < 8; ++jt) {
      float sv = S[jt][r];
      float pe = (sv > -1e29f) ? __expf(sv - mx) : 0.f;
      S[jt][r] = pe;
      sum += pe;
    }
    sum += __shfl_xor(sum, 1);
    sum += __shfl_xor(sum, 2);
    sum += __shfl_xor(sum, 4);
    sum += __shfl_xor(sum, 8);
    float inv = (sum > 0.f) ? (1.0f / sum) : 0.f;
    #pragma unroll
    for (int jt = 0; jt < 8; ++jt) {
      int row = h * 4 + r, col = jt * 16 + l15;
      _Float16 ph = (_Float16)(S[jt][r] * inv);
      *(_Float16*)((char*)p_lds + row * 256 + ((col << 1) ^ ((row & 7) << 4))) = ph;
    }
  }

  // ---- out = p @ vT^T : C[q][d], K = j(128) ----  (wave-local LDS; no barrier needed)
  half8 pa[4];
  #pragma unroll
  for (int ks = 0; ks < 4; ++ks) {
    int colh = ks * 32 + h * 8;
    pa[ks] = *(const half8*)((const char*)p_lds + l15 * 256 + ((colh << 1) ^ ((l15 & 7) << 4)));
  }
  const _Float16* vb = vT + (size_t)b * 512 * 8192;
  float* ob = out + (size_t)(b * 8192 + c * 64 + w * 16) * 512;
  #pragma unroll 2
  for (int dt = 0; dt < 32; ++dt) {
    f32x4 o = {};
    #pragma unroll
    for (int ks = 0; ks < 4; ++ks) {
      int jg = jbase + ks * 32 + h * 8;
      if (jg < 0) jg = 0;                  // c==0 first half: p==0 exactly
      half8 bf = *(const half8*)(vb + (size_t)(dt * 16 + l15) * 8192 + jg);
      o = MFMA(pa[ks], bf, o);
    }
    #pragma unroll
    for (int r = 0; r < 4; ++r)
      ob[(size_t)(h * 4 + r) * 512 + dt * 16 + l15] = o[r];
  }
}

// ================= fallback: round-1 fused kernel (used only if ws too small) =================
__device__ __forceinline__ int swz(int row, int colByte) {
  return colByte ^ ((row & 7) << 4);
}
__device__ __forceinline__ half8 ldw_frag(const float* __restrict__ W, int row, int e0) {
  const float4* p = reinterpret_cast<const float4*>(W + ((size_t)row << 9) + e0);
  float4 f0 = p[0];
  float4 f1 = p[1];
  half8 v;
  v[0] = (_Float16)f0.x; v[1] = (_Float16)f0.y; v[2] = (_Float16)f0.z; v[3] = (_Float16)f0.w;
  v[4] = (_Float16)f1.x; v[5] = (_Float16)f1.y; v[6] = (_Float16)f1.z; v[7] = (_Float16)f1.w;
  return v;
}
__device__ __forceinline__ half8 ldl_frag(const unsigned short* buf, int row, int col, int strideBytes) {
  int byte = row * strideBytes + swz(row, col << 1);
  return *reinterpret_cast<const half8*>(reinterpret_cast<const char*>(buf) + byte);
}

__global__ __launch_bounds__(256, 1)
void ep_fused(const float* __restrict__ x, const float* __restrict__ Wq,
              const float* __restrict__ Wk, const float* __restrict__ Wv,
              float* __restrict__ out)
{
  __shared__ unsigned short xs[128 * 512];
  __shared__ unsigned short kv[64 * 128];
  __shared__ unsigned short pq[64 * 128];

  const int bc   = blockIdx.x;
  const int b    = bc >> 7;
  const int c    = bc & (NCH - 1);
  const int tid  = threadIdx.x;
  const int lane = tid & 63;
  const int w    = tid >> 6;
  const int l15  = lane & 15;
  const int h    = lane >> 4;

  const float* xb = x + (size_t)b * (SEQ * DDIM);
  #pragma unroll
  for (int i = 0; i < 32; ++i) {
    int unit = tid + (i << 8);
    int row  = unit >> 6;
    int e0   = (unit & 63) << 3;
    half8 v;
    if (c == 0 && row < 64) {
      #pragma unroll
      for (int t = 0; t < 8; ++t) v[t] = (_Float16)0.0f;
    } else {
      int s = c * 64 - 64 + row;
      const float4* p = reinterpret_cast<const float4*>(xb + (size_t)s * DDIM + e0);
      float4 f0 = p[0], f1 = p[1];
      v[0] = (_Float16)f0.x; v[1] = (_Float16)f0.y; v[2] = (_Float16)f0.z; v[3] = (_Float16)f0.w;
      v[4] = (_Float16)f1.x; v[5] = (_Float16)f1.y; v[6] = (_Float16)f1.z; v[7] = (_Float16)f1.w;
    }
    int byte = (row << 10) + swz(row, e0 << 1);
    *reinterpret_cast<half8*>(reinterpret_cast<char*>(xs) + byte) = v;
  }
  __syncthreads();

  f32x4 Sacc[8] = {};
  const int d0 = (w << 4) + (h << 2);

  for (int dt = 0; dt < 8; ++dt) {
    const int drow = (dt << 6) + (w << 4) + l15;

    f32x4 qa[4] = {};
    for (int ks = 0; ks < 16; ++ks) {
      half8 a = ldw_frag(Wq, drow, (ks << 5) + (h << 3));
      #pragma unroll
      for (int nt = 0; nt < 4; ++nt) {
        half8 bf = ldl_frag(xs, 64 + (nt << 4) + l15, (ks << 5) + (h << 3), 1024);
        qa[nt] = MFMA(a, bf, qa[nt]);
      }
    }
    #pragma unroll
    for (int nt = 0; nt < 4; ++nt) {
      int q = (nt << 4) + l15;
      half4 hv;
      hv[0] = (_Float16)qa[nt][0]; hv[1] = (_Float16)qa[nt][1];
      hv[2] = (_Float16)qa[nt][2]; hv[3] = (_Float16)qa[nt][3];
      *reinterpret_cast<half4*>(reinterpret_cast<char*>(pq) + q * 128 + swz(q, d0 << 1)) = hv;
    }

    f32x4 ka[8] = {};
    for (int ks = 0; ks < 16; ++ks) {
      half8 a = ldw_frag(Wk, drow, (ks << 5) + (h << 3));
      #pragma unroll
      for (int nt = 0; nt < 8; ++nt) {
        half8 bf = ldl_frag(xs, (nt << 4) + l15, (ks << 5) + (h << 3), 1024);
        ka[nt] = MFMA(a, bf, ka[nt]);
      }
    }
    #pragma unroll
    for (int nt = 0; nt < 8; ++nt) {
      int j = (nt << 4) + l15;
      half4 hv;
      hv[0] = (_Float16)ka[nt][0]; hv[1] = (_Float16)ka[nt][1];
      hv[2] = (_Float16)ka[nt][2]; hv[3] = (_Float16)ka[nt][3];
      *reinterpret_cast<half4*>(reinterpret_cast<char*>(kv) + j * 128 + swz(j, d0 << 1)) = hv;
    }
    __syncthreads();

    #pragma unroll
    for (int ksd = 0; ksd < 2; ++ksd) {
      half8 a = ldl_frag(pq, (w << 4) + l15, (ksd << 5) + (h << 3), 128);
      #pragma unroll
      for (int nt = 0; nt < 8; ++nt) {
        half8 bf = ldl_frag(kv, (nt << 4) + l15, (ksd << 5) + (h << 3), 128);
        Sacc[nt] = MFMA(a, bf, Sacc[nt]);
      }
    }
    __syncthreads();
  }

  const float scale = SCALE;
  #pragma unroll
  for (int nt = 0; nt < 8; ++nt) {
    int j = (nt << 4) + l15;
    #pragma unroll
    for (int r = 0; r < 4; ++r) {
      int qrow = (w << 4) + (h << 2) + r;
      bool valid = (j < 64 + qrow) && ((c > 0) || (j >= 64));
      Sacc[nt][r] = valid ? Sacc[nt][r] * scale : -1e30f;
    }
  }
  float inv[4];
  #pragma unroll
  for (int r = 0; r < 4; ++r) {
    float mx = -1e30f;
    #pragma unroll
    for (int nt = 0; nt < 8; ++nt) mx = fmaxf(mx, Sacc[nt][r]);
    mx = fmaxf(mx, __shfl_xor(mx, 1));
    mx = fmaxf(mx, __shfl_xor(mx, 2));
    mx = fmaxf(mx, __shfl_xor(mx, 4));
    mx = fmaxf(mx, __shfl_xor(mx, 8));
    float sum = 0.f;
    #pragma unroll
    for (int nt = 0; nt < 8; ++nt) {
      float sv = Sacc[nt][r];
      float pe = (sv > -1e29f) ? __expf(sv - mx) : 0.f;
      Sacc[nt][r] = pe;
      sum += pe;
    }
    sum += __shfl_xor(sum, 1);
    sum += __shfl_xor(sum, 2);
    sum += __shfl_xor(sum, 4);
    sum += __shfl_xor(sum, 8);
    inv[r] = (sum > 0.f) ? (1.0f / sum) : 0.f;
  }
  #pragma unroll
  for (int nt = 0; nt < 8; ++nt) {
    int j = (nt << 4) + l15;
    #pragma unroll
    for (int r = 0; r < 4; ++r) {
      int qrow = (w << 4) + (h << 2) + r;
      _Float16 ph = (_Float16)(Sacc[nt][r] * inv[r]);
      *reinterpret_cast<_Float16*>(reinterpret_cast<char*>(pq) + qrow * 256 + swz(qrow, j << 1)) = ph;
    }
  }
  __syncthreads();

  for (int dt = 0; dt < 8; ++dt) {
    const int dcol = (dt << 6) + (w << 4) + l15;

    f32x4 va[8] = {};
    for (int ks = 0; ks < 16; ++ks) {
      half8 bf = ldw_frag(Wv, dcol, (ks << 5) + (h << 3));
      #pragma unroll
      for (int mt = 0; mt < 8; ++mt) {
        half8 a = ldl_frag(xs, (mt << 4) + l15, (ks << 5) + (h << 3), 1024);
        va[mt] = MFMA(a, bf, va[mt]);
      }
    }
    {
      int dl = (w << 4) + l15;
      #pragma unroll
      for (int mt = 0; mt < 8; ++mt) {
        int j0 = (mt << 4) + (h << 2);
        half4 hv;
        hv[0] = (_Float16)va[mt][0]; hv[1] = (_Float16)va[mt][1];
        hv[2] = (_Float16)va[mt][2]; hv[3] = (_Float16)va[mt][3];
        *reinterpret_cast<half4*>(reinterpret_cast<char*>(kv) + dl * 256 + swz(dl, j0 << 1)) = hv;
      }
    }
    __syncthreads();

    f32x4 oa[4] = {};
    #pragma unroll
    for (int ks = 0; ks < 4; ++ks) {
      half8 a = ldl_frag(pq, (w << 4) + l15, (ks << 5) + (h << 3), 256);
      #pragma unroll
      for (int nt = 0; nt < 4; ++nt) {
        half8 bf = ldl_frag(kv, (nt << 4) + l15, (ks << 5) + (h << 3), 256);
        oa[nt] = MFMA(a, bf, oa[nt]);
      }
    }
    #pragma unroll
    for (int nt = 0; nt < 4; ++nt) {
      int d = (dt << 6) + (nt << 4) + l15;
      #pragma unroll
      for (int r = 0; r < 4; ++r) {
        int qrow = (w << 4) + (h << 2) + r;
        out[((size_t)(b * SEQ + (c << 6) + qrow) << 9) + d] = oa[nt][r];
      }
    }
    __syncthreads();
  }
}

extern "C" void kernel_launch(void* const* d_in, const int* in_sizes, int n_in,
                              void* d_out, int out_size, void* d_ws, size_t ws_size,
                              hipStream_t stream) {
  const float* x  = (const float*)d_in[0];
  const float* Wq = (const float*)d_in[1];
  const float* Wk = (const float*)d_in[2];
  const float* Wv = (const float*)d_in[3];
  float* out = (float*)d_out;
  (void)in_sizes; (void)n_in; (void)out_size;

  if (d_ws != nullptr && ws_size >= WS_NEED) {
    char* ws = (char*)d_ws;
    _Float16* x16 = (_Float16*)(ws + X16_OFF);
    _Float16* q16 = (_Float16*)(ws + Q16_OFF);
    _Float16* k16 = (_Float16*)(ws + K16_OFF);
    _Float16* vT  = (_Float16*)(ws + VT_OFF);
    _Float16* w16 = (_Float16*)(ws + W16_OFF);

    hipLaunchKernelGGL(k0_cvt, dim3(8576), dim3(256), 0, stream, x, Wq, Wk, Wv, x16, w16);
    hipLaunchKernelGGL(k1_gemm, dim3(256, 4, 3), dim3(256), 0, stream, x16, w16, q16, k16, vT);
    hipLaunchKernelGGL(k2_attn, dim3(2048), dim3(64), 0, stream, q16, k16, vT, out);
  } else {
    hipLaunchKernelGGL(ep_fused, dim3(4 * NCH), dim3(256), 0, stream, x, Wq, Wk, Wv, out);
  }
}

// Round 3
// 130.190 us; speedup vs baseline: 3.2344x; 1.9523x over previous
//
#include <hip/hip_runtime.h>

#define SCALE 0.044194173824159216f   // 1/sqrt(512)

typedef _Float16 half8 __attribute__((ext_vector_type(8)));
typedef _Float16 half4 __attribute__((ext_vector_type(4)));
typedef float    f32x4 __attribute__((ext_vector_type(4)));

#define MFMA(A, B, Cc) __builtin_amdgcn_mfma_f32_16x16x32_f16((A), (B), (Cc), 0, 0, 0)

// ---------------- ws layout (bytes) ----------------
#define X16_OFF 0ull
#define Q16_OFF 33554432ull
#define K16_OFF 67108864ull
#define VT_OFF  100663296ull
#define W16_OFF 134217728ull     // W_all fp16 [1536][512]: Wq~(scaled), Wk, Wv
#define WS_NEED 135790592ull

typedef __attribute__((address_space(1))) const unsigned int glb_t;
typedef __attribute__((address_space(3))) unsigned int lds_t;

// async global->LDS, 16B per lane; LDS dest = wave-uniform base + lane*16
__device__ __forceinline__ void gl16(const _Float16* g, _Float16* l) {
  __builtin_amdgcn_global_load_lds((glb_t*)g, (lds_t*)l, 16, 0, 0);
}

// swizzled read of a [R][64] fp16 tile (row stride 128B): LDS[row][u] = glob[row][u^(row&7)]
__device__ __forceinline__ half8 ldf64(const _Float16* buf, int row, int colh) {
  int byte = row * 128 + (((colh) << 1) ^ ((row & 7) << 4));
  return *(const half8*)((const char*)buf + byte);
}
// swizzled read of a [R][128] fp16 tile (row stride 256B): unit bits 0..2 XOR (row&7)
__device__ __forceinline__ half8 ldf128(const _Float16* buf, int row, int colh) {
  int byte = row * 256 + (((colh) << 1) ^ ((row & 7) << 4));
  return *(const half8*)((const char*)buf + byte);
}

// ================= K0: fp32 -> fp16 convert (x; W with 1/sqrt(D) folded into Wq) =================
__global__ __launch_bounds__(256)
void k0_cvt(const float* __restrict__ x, const float* __restrict__ Wq,
            const float* __restrict__ Wk, const float* __restrict__ Wv,
            _Float16* __restrict__ x16, _Float16* __restrict__ w16)
{
  const long long NX = 16777216LL;   // 4*8192*512
  long long base = ((long long)blockIdx.x * 256 + threadIdx.x) * 8;
  const float* src;
  _Float16* dst;
  float sc = 1.0f;
  if (base < NX) {
    src = x + base; dst = x16 + base;
  } else {
    long long o = base - NX;             // 0 .. 786431
    int ws = (int)(o >> 18);             // /262144
    long long oo = o & 262143LL;
    src = (ws == 0 ? Wq : (ws == 1 ? Wk : Wv)) + oo;
    dst = w16 + o;
    if (ws == 0) sc = SCALE;
  }
  const float4* p = (const float4*)src;
  float4 f0 = p[0], f1 = p[1];
  half8 v;
  v[0] = (_Float16)(f0.x * sc); v[1] = (_Float16)(f0.y * sc);
  v[2] = (_Float16)(f0.z * sc); v[3] = (_Float16)(f0.w * sc);
  v[4] = (_Float16)(f1.x * sc); v[5] = (_Float16)(f1.y * sc);
  v[6] = (_Float16)(f1.z * sc); v[7] = (_Float16)(f1.w * sc);
  *(half8*)dst = v;
}

// ================= K1: m97-style 128x128 GEMM, gload_lds staged, src-swizzled =================
// C = x[32768,512] @ W_all[1536,512]^T ; ntile 0..3 -> q, 4..7 -> k, 8..11 -> vT(transposed store)
__global__ __launch_bounds__(256)
void k1_gemm(const _Float16* __restrict__ x16, const _Float16* __restrict__ w16,
             _Float16* __restrict__ q16, _Float16* __restrict__ k16,
             _Float16* __restrict__ vT)
{
  __shared__ _Float16 xs[128 * 64];   // 16KB, [128 s][64 e], src-swizzled
  __shared__ _Float16 wl[128 * 64];   // 16KB, [128 n][64 e], src-swizzled

  const int ntile = blockIdx.x;       // 0..11 (major: 12 blocks share one x-tile)
  const int stile = blockIdx.y;       // 0..255
  const int wsel  = ntile >> 2;
  const int tid = threadIdx.x, lane = tid & 63, w = tid >> 6;
  const int l15 = lane & 15, h = lane >> 4;
  const int wm = w >> 1, wn = w & 1;

  const _Float16* xb = x16 + (size_t)stile * 128 * 512;
  const _Float16* wb = w16 + (size_t)ntile * 128 * 512;

  // staging map: unit = i*256 + w*64 + lane ; row = unit>>3 ; src col-unit = u ^ (row&7)
  int rowi[4], coli[4];
  #pragma unroll
  for (int i = 0; i < 4; ++i) {
    int unit = i * 256 + w * 64 + lane;
    int row = unit >> 3, u = unit & 7;
    rowi[i] = row;
    coli[i] = (u ^ (row & 7)) << 3;   // fp16 elements within the 64-wide slice
  }

  f32x4 acc[4][4] = {};
  const bool vpath = (wsel == 2);

  for (int kk = 0; kk < 8; ++kk) {
    __syncthreads();                  // all waves done reading previous tiles
    #pragma unroll
    for (int i = 0; i < 4; ++i) {
      int ub = i * 256 + w * 64;      // wave-uniform unit base
      gl16(xb + (size_t)rowi[i] * 512 + kk * 64 + coli[i], &xs[ub * 8]);
      gl16(wb + (size_t)rowi[i] * 512 + kk * 64 + coli[i], &wl[ub * 8]);
    }
    __syncthreads();                  // drains vmcnt(0): tiles ready

    #pragma unroll
    for (int ks = 0; ks < 2; ++ks) {
      half8 a[4], bf[4];
      if (!vpath) {
        #pragma unroll
        for (int mr = 0; mr < 4; ++mr) a[mr]  = ldf64(xs, wm * 64 + mr * 16 + l15, ks * 32 + h * 8);
        #pragma unroll
        for (int nr = 0; nr < 4; ++nr) bf[nr] = ldf64(wl, wn * 64 + nr * 16 + l15, ks * 32 + h * 8);
      } else {
        #pragma unroll
        for (int mr = 0; mr < 4; ++mr) a[mr]  = ldf64(wl, wm * 64 + mr * 16 + l15, ks * 32 + h * 8);
        #pragma unroll
        for (int nr = 0; nr < 4; ++nr) bf[nr] = ldf64(xs, wn * 64 + nr * 16 + l15, ks * 32 + h * 8);
      }
      #pragma unroll
      for (int mr = 0; mr < 4; ++mr)
        #pragma unroll
        for (int nr = 0; nr < 4; ++nr)
          acc[mr][nr] = MFMA(a[mr], bf[nr], acc[mr][nr]);
    }
  }

  if (!vpath) {
    _Float16* dst = (wsel == 0) ? q16 : k16;
    const int m0 = stile * 128 + wm * 64;
    const int n0 = (ntile & 3) * 128 + wn * 64;
    #pragma unroll
    for (int mr = 0; mr < 4; ++mr)
      #pragma unroll
      for (int nr = 0; nr < 4; ++nr)
        #pragma unroll
        for (int r = 0; r < 4; ++r)
          dst[(size_t)(m0 + mr * 16 + h * 4 + r) * 512 + n0 + nr * 16 + l15] =
              (_Float16)acc[mr][nr][r];
  } else {
    const int d0 = (ntile & 3) * 128 + wm * 64;
    const int sg = stile * 128 + wn * 64;
    const int bb = sg >> 13, s0 = sg & 8191;
    _Float16* dst = vT + (size_t)bb * 512 * 8192;
    #pragma unroll
    for (int mr = 0; mr < 4; ++mr)
      #pragma unroll
      for (int nr = 0; nr < 4; ++nr)
        #pragma unroll
        for (int r = 0; r < 4; ++r)
          dst[(size_t)(d0 + mr * 16 + h * 4 + r) * 8192 + s0 + nr * 16 + l15] =
              (_Float16)acc[mr][nr][r];
  }
}

// ================= K2: chunked attention, 4 waves per (b,c), staged k/vT, db pipeline =================
__global__ __launch_bounds__(256)
void k2_attn(const _Float16* __restrict__ q16, const _Float16* __restrict__ k16,
             const _Float16* __restrict__ vT, float* __restrict__ out)
{
  __shared__ _Float16 kj[2][128 * 64];   // 2x16KB: S: [128 j][64 e] ; PV: [64 d][128 j]
  __shared__ _Float16 p_lds[64 * 128];   // 16KB, [64 q][128 j], swizzled, wave-local use

  const int bx = blockIdx.x;
  const int b = bx >> 7, c = bx & 127;
  const int tid = threadIdx.x, lane = tid & 63, w = tid >> 6;
  const int l15 = lane & 15, h = lane >> 4;
  const int jbase = c * 64 - 64;

  // q rows for this wave -> registers (16 x half8 = 64 VGPR), scale pre-folded
  const _Float16* qrow = q16 + (size_t)(b * 8192 + c * 64 + w * 16 + l15) * 512;
  half8 qa[16];
  #pragma unroll
  for (int ks = 0; ks < 16; ++ks) qa[ks] = *(const half8*)(qrow + ks * 32 + h * 8);

  const _Float16* kb = k16 + (size_t)b * 8192 * 512;

  // ---- S phase: e-loop, double-buffered k-slices ----
  f32x4 S[8] = {};
  {
    // prologue stage ee=0 into buf 0
    #pragma unroll
    for (int i = 0; i < 4; ++i) {
      int unit = i * 256 + w * 64 + lane;
      int row = unit >> 3, u = unit & 7;
      int sj = jbase + row; if (sj < 0) sj = 0;
      gl16(kb + (size_t)sj * 512 + ((u ^ (row & 7)) << 3), &kj[0][(i * 256 + w * 64) * 8]);
    }
    int cur = 0;
    for (int ee = 0; ee < 8; ++ee) {
      __syncthreads();                 // drain stage(cur); waves done reading cur^1
      if (ee < 7) {
        #pragma unroll
        for (int i = 0; i < 4; ++i) {
          int unit = i * 256 + w * 64 + lane;
          int row = unit >> 3, u = unit & 7;
          int sj = jbase + row; if (sj < 0) sj = 0;
          gl16(kb + (size_t)sj * 512 + (ee + 1) * 64 + ((u ^ (row & 7)) << 3),
               &kj[cur ^ 1][(i * 256 + w * 64) * 8]);
        }
      }
      #pragma unroll
      for (int ks = 0; ks < 2; ++ks) {
        #pragma unroll
        for (int nt = 0; nt < 8; ++nt) {
          half8 bf = ldf64(kj[cur], nt * 16 + l15, ks * 32 + h * 8);
          S[nt] = MFMA(qa[ee * 2 + ks], bf, S[nt]);
        }
      }
      cur ^= 1;
    }
  }

  // ---- masked softmax (row q = h*4+r within this wave's 16 rows) ----
  #pragma unroll
  for (int jt = 0; jt < 8; ++jt) {
    int j = jt * 16 + l15;
    #pragma unroll
    for (int r = 0; r < 4; ++r) {
      int ql = w * 16 + h * 4 + r;
      bool valid = (j < 64 + ql) && ((c > 0) || (j >= 64));
      S[jt][r] = valid ? S[jt][r] : -1e30f;
    }
  }
  #pragma unroll
  for (int r = 0; r < 4; ++r) {
    float mx = -1e30f;
    #pragma unroll
    for (int jt = 0; jt < 8; ++jt) mx = fmaxf(mx, S[jt][r]);
    mx = fmaxf(mx, __shfl_xor(mx, 1));
    mx = fmaxf(mx, __shfl_xor(mx, 2));
    mx = fmaxf(mx, __shfl_xor(mx, 4));
    mx = fmaxf(mx, __shfl_xor(mx, 8));
    float sum = 0.f;
    #pragma unroll
    for (int jt = 0; jt < 8; ++jt) {
      float sv = S[jt][r];
      float pe = (sv > -1e29f) ? __expf(sv - mx) : 0.f;
      S[jt][r] = pe;
      sum += pe;
    }
    sum += __shfl_xor(sum, 1);
    sum += __shfl_xor(sum, 2);
    sum += __shfl_xor(sum, 4);
    sum += __shfl_xor(sum, 8);
    float inv = (sum > 0.f) ? (1.0f / sum) : 0.f;   // fully-masked row -> p = 0
    #pragma unroll
    for (int jt = 0; jt < 8; ++jt) {
      int row = w * 16 + h * 4 + r, col = jt * 16 + l15;
      _Float16 ph = (_Float16)(S[jt][r] * inv);
      *(_Float16*)((char*)p_lds + row * 256 + ((col << 1) ^ ((row & 7) << 4))) = ph;
    }
  }
  // p A-frags (wave-local RAW; compiler inserts lgkmcnt wait)
  half8 pa[4];
  #pragma unroll
  for (int ks = 0; ks < 4; ++ks) {
    int row = w * 16 + l15, colh = ks * 32 + h * 8;
    pa[ks] = *(const half8*)((const char*)p_lds + row * 256 + ((colh << 1) ^ ((row & 7) << 4)));
  }

  // ---- PV phase: d-loop, double-buffered vT-slices [64 d][128 j] ----
  const _Float16* vb = vT + (size_t)b * 512 * 8192;
  float* ob = out + (size_t)(b * 8192 + c * 64 + w * 16) * 512;

  __syncthreads();                     // everyone done with S-phase kj reads
  #pragma unroll
  for (int i = 0; i < 4; ++i) {        // prologue stage dd=0 into buf 0
    int unit = i * 256 + w * 64 + lane;
    int row = unit >> 4, u = unit & 15;
    int u2 = (u & 8) | ((u & 7) ^ (row & 7));
    int js = jbase + u2 * 8; if (js < 0) js = 0;
    gl16(vb + (size_t)row * 8192 + js, &kj[0][(i * 256 + w * 64) * 8]);
  }
  int cur = 0;
  for (int dd = 0; dd < 8; ++dd) {
    __syncthreads();                   // drain stage(cur); waves done reading cur^1
    if (dd < 7) {
      #pragma unroll
      for (int i = 0; i < 4; ++i) {
        int unit = i * 256 + w * 64 + lane;
        int row = unit >> 4, u = unit & 15;
        int u2 = (u & 8) | ((u & 7) ^ (row & 7));
        int js = jbase + u2 * 8; if (js < 0) js = 0;
        gl16(vb + (size_t)((dd + 1) * 64 + row) * 8192 + js, &kj[cur ^ 1][(i * 256 + w * 64) * 8]);
      }
    }
    f32x4 o[4] = {};
    #pragma unroll
    for (int ks = 0; ks < 4; ++ks) {
      #pragma unroll
      for (int nr = 0; nr < 4; ++nr) {
        half8 bf = ldf128(kj[cur], nr * 16 + l15, ks * 32 + h * 8);
        o[nr] = MFMA(pa[ks], bf, o[nr]);
      }
    }
    #pragma unroll
    for (int nr = 0; nr < 4; ++nr)
      #pragma unroll
      for (int r = 0; r < 4; ++r)
        ob[(size_t)(h * 4 + r) * 512 + dd * 64 + nr * 16 + l15] = o[nr][r];
    cur ^= 1;
  }
}

// ================= fallback: round-1 fused kernel (used only if ws too small) =================
__device__ __forceinline__ int swz(int row, int colByte) {
  return colByte ^ ((row & 7) << 4);
}
__device__ __forceinline__ half8 ldw_frag(const float* __restrict__ W, int row, int e0) {
  const float4* p = reinterpret_cast<const float4*>(W + ((size_t)row << 9) + e0);
  float4 f0 = p[0];
  float4 f1 = p[1];
  half8 v;
  v[0] = (_Float16)f0.x; v[1] = (_Float16)f0.y; v[2] = (_Float16)f0.z; v[3] = (_Float16)f0.w;
  v[4] = (_Float16)f1.x; v[5] = (_Float16)f1.y; v[6] = (_Float16)f1.z; v[7] = (_Float16)f1.w;
  return v;
}
__device__ __forceinline__ half8 ldl_frag(const unsigned short* buf, int row, int col, int strideBytes) {
  int byte = row * strideBytes + swz(row, col << 1);
  return *reinterpret_cast<const half8*>(reinterpret_cast<const char*>(buf) + byte);
}

__global__ __launch_bounds__(256, 1)
void ep_fused(const float* __restrict__ x, const float* __restrict__ Wq,
              const float* __restrict__ Wk, const float* __restrict__ Wv,
              float* __restrict__ out)
{
  __shared__ unsigned short xs[128 * 512];
  __shared__ unsigned short kv[64 * 128];
  __shared__ unsigned short pq[64 * 128];

  const int bc   = blockIdx.x;
  const int b    = bc >> 7;
  const int c    = bc & 127;
  const int tid  = threadIdx.x;
  const int lane = tid & 63;
  const int w    = tid >> 6;
  const int l15  = lane & 15;
  const int h    = lane >> 4;

  const float* xb = x + (size_t)b * (8192 * 512);
  #pragma unroll
  for (int i = 0; i < 32; ++i) {
    int unit = tid + (i << 8);
    int row  = unit >> 6;
    int e0   = (unit & 63) << 3;
    half8 v;
    if (c == 0 && row < 64) {
      #pragma unroll
      for (int t = 0; t < 8; ++t) v[t] = (_Float16)0.0f;
    } else {
      int s = c * 64 - 64 + row;
      const float4* p = reinterpret_cast<const float4*>(xb + (size_t)s * 512 + e0);
      float4 f0 = p[0], f1 = p[1];
      v[0] = (_Float16)f0.x; v[1] = (_Float16)f0.y; v[2] = (_Float16)f0.z; v[3] = (_Float16)f0.w;
      v[4] = (_Float16)f1.x; v[5] = (_Float16)f1.y; v[6] = (_Float16)f1.z; v[7] = (_Float16)f1.w;
    }
    int byte = (row << 10) + swz(row, e0 << 1);
    *reinterpret_cast<half8*>(reinterpret_cast<char*>(xs) + byte) = v;
  }
  __syncthreads();

  f32x4 Sacc[8] = {};
  const int d0 = (w << 4) + (h << 2);

  for (int dt = 0; dt < 8; ++dt) {
    const int drow = (dt << 6) + (w << 4) + l15;

    f32x4 qa[4] = {};
    for (int ks = 0; ks < 16; ++ks) {
      half8 a = ldw_frag(Wq, drow, (ks << 5) + (h << 3));
      #pragma unroll
      for (int nt = 0; nt < 4; ++nt) {
        half8 bf = ldl_frag(xs, 64 + (nt << 4) + l15, (ks << 5) + (h << 3), 1024);
        qa[nt] = MFMA(a, bf, qa[nt]);
      }
    }
    #pragma unroll
    for (int nt = 0; nt < 4; ++nt) {
      int q = (nt << 4) + l15;
      half4 hv;
      hv[0] = (_Float16)qa[nt][0]; hv[1] = (_Float16)qa[nt][1];
      hv[2] = (_Float16)qa[nt][2]; hv[3] = (_Float16)qa[nt][3];
      *reinterpret_cast<half4*>(reinterpret_cast<char*>(pq) + q * 128 + swz(q, d0 << 1)) = hv;
    }

    f32x4 ka[8] = {};
    for (int ks = 0; ks < 16; ++ks) {
      half8 a = ldw_frag(Wk, drow, (ks << 5) + (h << 3));
      #pragma unroll
      for (int nt = 0; nt < 8; ++nt) {
        half8 bf = ldl_frag(xs, (nt << 4) + l15, (ks << 5) + (h << 3), 1024);
        ka[nt] = MFMA(a, bf, ka[nt]);
      }
    }
    #pragma unroll
    for (int nt = 0; nt < 8; ++nt) {
      int j = (nt << 4) + l15;
      half4 hv;
      hv[0] = (_Float16)ka[nt][0]; hv[1] = (_Float16)ka[nt][1];
      hv[2] = (_Float16)ka[nt][2]; hv[3] = (_Float16)ka[nt][3];
      *reinterpret_cast<half4*>(reinterpret_cast<char*>(kv) + j * 128 + swz(j, d0 << 1)) = hv;
    }
    __syncthreads();

    #pragma unroll
    for (int ksd = 0; ksd < 2; ++ksd) {
      half8 a = ldl_frag(pq, (w << 4) + l15, (ksd << 5) + (h << 3), 128);
      #pragma unroll
      for (int nt = 0; nt < 8; ++nt) {
        half8 bf = ldl_frag(kv, (nt << 4) + l15, (ksd << 5) + (h << 3), 128);
        Sacc[nt] = MFMA(a, bf, Sacc[nt]);
      }
    }
    __syncthreads();
  }

  const float scale = SCALE;
  #pragma unroll
  for (int nt = 0; nt < 8; ++nt) {
    int j = (nt << 4) + l15;
    #pragma unroll
    for (int r = 0; r < 4; ++r) {
      int qrow = (w << 4) + (h << 2) + r;
      bool valid = (j < 64 + qrow) && ((c > 0) || (j >= 64));
      Sacc[nt][r] = valid ? Sacc[nt][r] * scale : -1e30f;
    }
  }
  float inv[4];
  #pragma unroll
  for (int r = 0; r < 4; ++r) {
    float mx = -1e30f;
    #pragma unroll
    for (int nt = 0; nt < 8; ++nt) mx = fmaxf(mx, Sacc[nt][r]);
    mx = fmaxf(mx, __shfl_xor(mx, 1));
    mx = fmaxf(mx, __shfl_xor(mx, 2));
    mx = fmaxf(mx, __shfl_xor(mx, 4));
    mx = fmaxf(mx, __shfl_xor(mx, 8));
    float sum = 0.f;
    #pragma unroll
    for (int nt = 0; nt < 8; ++nt) {
      float sv = Sacc[nt][r];
      float pe = (sv > -1e29f) ? __expf(sv - mx) : 0.f;
      Sacc[nt][r] = pe;
      sum += pe;
    }
    sum += __shfl_xor(sum, 1);
    sum += __shfl_xor(sum, 2);
    sum += __shfl_xor(sum, 4);
    sum += __shfl_xor(sum, 8);
    inv[r] = (sum > 0.f) ? (1.0f / sum) : 0.f;
  }
  #pragma unroll
  for (int nt = 0; nt < 8; ++nt) {
    int j = (nt << 4) + l15;
    #pragma unroll
    for (int r = 0; r < 4; ++r) {
      int qrow = (w << 4) + (h << 2) + r;
      _Float16 ph = (_Float16)(Sacc[nt][r] * inv[r]);
      *reinterpret_cast<_Float16*>(reinterpret_cast<char*>(pq) + qrow * 256 + swz(qrow, j << 1)) = ph;
    }
  }
  __syncthreads();

  for (int dt = 0; dt < 8; ++dt) {
    const int dcol = (dt << 6) + (w << 4) + l15;

    f32x4 va[8] = {};
    for (int ks = 0; ks < 16; ++ks) {
      half8 bf = ldw_frag(Wv, dcol, (ks << 5) + (h << 3));
      #pragma unroll
      for (int mt = 0; mt < 8; ++mt) {
        half8 a = ldl_frag(xs, (mt << 4) + l15, (ks << 5) + (h << 3), 1024);
        va[mt] = MFMA(a, bf, va[mt]);
      }
    }
    {
      int dl = (w << 4) + l15;
      #pragma unroll
      for (int mt = 0; mt < 8; ++mt) {
        int j0 = (mt << 4) + (h << 2);
        half4 hv;
        hv[0] = (_Float16)va[mt][0]; hv[1] = (_Float16)va[mt][1];
        hv[2] = (_Float16)va[mt][2]; hv[3] = (_Float16)va[mt][3];
        *reinterpret_cast<half4*>(reinterpret_cast<char*>(kv) + dl * 256 + swz(dl, j0 << 1)) = hv;
      }
    }
    __syncthreads();

    f32x4 oa[4] = {};
    #pragma unroll
    for (int ks = 0; ks < 4; ++ks) {
      half8 a = ldl_frag(pq, (w << 4) + l15, (ks << 5) + (h << 3), 256);
      #pragma unroll
      for (int nt = 0; nt < 4; ++nt) {
        half8 bf = ldl_frag(kv, (nt << 4) + l15, (ks << 5) + (h << 3), 256);
        oa[nt] = MFMA(a, bf, oa[nt]);
      }
    }
    #pragma unroll
    for (int nt = 0; nt < 4; ++nt) {
      int d = (dt << 6) + (nt << 4) + l15;
      #pragma unroll
      for (int r = 0; r < 4; ++r) {
        int qrow = (w << 4) + (h << 2) + r;
        out[((size_t)(b * 8192 + (c << 6) + qrow) << 9) + d] = oa[nt][r];
      }
    }
    __syncthreads();
  }
}

extern "C" void kernel_launch(void* const* d_in, const int* in_sizes, int n_in,
                              void* d_out, int out_size, void* d_ws, size_t ws_size,
                              hipStream_t stream) {
  const float* x  = (const float*)d_in[0];
  const float* Wq = (const float*)d_in[1];
  const float* Wk = (const float*)d_in[2];
  const float* Wv = (const float*)d_in[3];
  float* out = (float*)d_out;
  (void)in_sizes; (void)n_in; (void)out_size;

  if (d_ws != nullptr && ws_size >= WS_NEED) {
    char* ws = (char*)d_ws;
    _Float16* x16 = (_Float16*)(ws + X16_OFF);
    _Float16* q16 = (_Float16*)(ws + Q16_OFF);
    _Float16* k16 = (_Float16*)(ws + K16_OFF);
    _Float16* vT  = (_Float16*)(ws + VT_OFF);
    _Float16* w16 = (_Float16*)(ws + W16_OFF);

    hipLaunchKernelGGL(k0_cvt, dim3(8576), dim3(256), 0, stream, x, Wq, Wk, Wv, x16, w16);
    hipLaunchKernelGGL(k1_gemm, dim3(12, 256), dim3(256), 0, stream, x16, w16, q16, k16, vT);
    hipLaunchKernelGGL(k2_attn, dim3(512), dim3(256), 0, stream, q16, k16, vT, out);
  } else {
    hipLaunchKernelGGL(ep_fused, dim3(512), dim3(256), 0, stream, x, Wq, Wk, Wv, out);
  }
}

// Round 4
// 122.856 us; speedup vs baseline: 3.4275x; 1.0597x over previous
//
#include <hip/hip_runtime.h>

#define SCALE 0.044194173824159216f   // 1/sqrt(512)

typedef _Float16 half8 __attribute__((ext_vector_type(8)));
typedef _Float16 half4 __attribute__((ext_vector_type(4)));
typedef float    f32x4 __attribute__((ext_vector_type(4)));

#define MFMA(A, B, Cc) __builtin_amdgcn_mfma_f32_16x16x32_f16((A), (B), (Cc), 0, 0, 0)

// ---------------- ws layout (bytes) ----------------
#define X16_OFF 0ull            // (unused now)
#define Q16_OFF 33554432ull
#define K16_OFF 67108864ull
#define VT_OFF  100663296ull
#define W16_OFF 134217728ull    // W_all fp16 [1536][512]: Wq~(scaled), Wk, Wv
#define WS_NEED 135790592ull

typedef __attribute__((address_space(1))) const unsigned int glb_t;
typedef __attribute__((address_space(3))) unsigned int lds_t;

// async global->LDS, 16B per lane; LDS dest = wave-uniform base + lane*16
__device__ __forceinline__ void gl16(const void* g, void* l) {
  __builtin_amdgcn_global_load_lds((glb_t*)g, (lds_t*)l, 16, 0, 0);
}

// swizzled read of a [R][64] fp16 tile (row stride 128B): LDS[row][u16] = glob[row][u16^(row&7)]
__device__ __forceinline__ half8 ldf64(const _Float16* buf, int row, int colh) {
  int byte = row * 128 + (((colh) << 1) ^ ((row & 7) << 4));
  return *(const half8*)((const char*)buf + byte);
}
// swizzled read of a [R][128] fp16 tile (row stride 256B)
__device__ __forceinline__ half8 ldf128(const _Float16* buf, int row, int colh) {
  int byte = row * 256 + (((colh) << 1) ^ ((row & 7) << 4));
  return *(const half8*)((const char*)buf + byte);
}
// swizzled read of a [R][64] fp32 tile (row stride 256B, 32B-granular swizzle) + cvt to fp16 frag
__device__ __forceinline__ half8 ldx32(const float* buf, int row, int e0) {
  int byte = row * 256 + ((e0 << 2) ^ ((row & 7) << 5));
  const char* p = (const char*)buf + byte;
  f32x4 f0 = *(const f32x4*)p;
  f32x4 f1 = *(const f32x4*)(p + 16);
  half8 v;
  v[0] = (_Float16)f0[0]; v[1] = (_Float16)f0[1]; v[2] = (_Float16)f0[2]; v[3] = (_Float16)f0[3];
  v[4] = (_Float16)f1[0]; v[5] = (_Float16)f1[1]; v[6] = (_Float16)f1[2]; v[7] = (_Float16)f1[3];
  return v;
}

// ================= K0: W fp32 -> fp16 (1/sqrt(D) folded into Wq); tiny =================
__global__ __launch_bounds__(256)
void k0_cvtW(const float* __restrict__ Wq, const float* __restrict__ Wk,
             const float* __restrict__ Wv, _Float16* __restrict__ w16)
{
  long long o = ((long long)blockIdx.x * 256 + threadIdx.x) * 8;   // 0 .. 786431
  int ws = (int)(o >> 18);
  long long oo = o & 262143LL;
  const float* src = (ws == 0 ? Wq : (ws == 1 ? Wk : Wv)) + oo;
  float sc = (ws == 0) ? SCALE : 1.0f;
  const float4* p = (const float4*)src;
  float4 f0 = p[0], f1 = p[1];
  half8 v;
  v[0] = (_Float16)(f0.x * sc); v[1] = (_Float16)(f0.y * sc);
  v[2] = (_Float16)(f0.z * sc); v[3] = (_Float16)(f0.w * sc);
  v[4] = (_Float16)(f1.x * sc); v[5] = (_Float16)(f1.y * sc);
  v[6] = (_Float16)(f1.z * sc); v[7] = (_Float16)(f1.w * sc);
  *(half8*)(w16 + o) = v;
}

// ================= K1: 128x128 GEMM, x read as fp32 directly, XCD-chunked =================
// C = x[32768,512] @ W_all[1536,512]^T ; ntile 0..3 -> q, 4..7 -> k, 8..11 -> vT(transposed store)
__global__ __launch_bounds__(256)
void k1_gemm(const float* __restrict__ x, const _Float16* __restrict__ w16,
             _Float16* __restrict__ q16, _Float16* __restrict__ k16,
             _Float16* __restrict__ vT)
{
  __shared__ float    xs[128 * 64];   // 32KB, [128 s][64 e] fp32, src-swizzled (32B gran)
  __shared__ _Float16 wl[128 * 64];   // 16KB, [128 n][64 e] fp16, src-swizzled (16B gran)

  // bijective XCD swizzle: 3072 blocks = 8 XCDs x 384; each XCD gets contiguous
  // stile chunk (32 stiles x 12 ntiles) -> every x-tile fetched on exactly 1 XCD.
  const int id  = blockIdx.x;
  const int swz = (id & 7) * 384 + (id >> 3);
  const int ntile = swz % 12;
  const int stile = swz / 12;
  const int wsel  = ntile >> 2;
  const int tid = threadIdx.x, lane = tid & 63, w = tid >> 6;
  const int l15 = lane & 15, h = lane >> 4;
  const int wm = w >> 1, wn = w & 1;

  const float*    xb = x   + (size_t)stile * 128 * 512;
  const _Float16* wb = w16 + (size_t)ntile * 128 * 512;

  // x staging map (fp32): 2048 units of 16B(4 f32); 16 units/row; swizzle bits1-3 of unit
  int xrow[8], xcol[8];
  #pragma unroll
  for (int i = 0; i < 8; ++i) {
    int unit = i * 256 + w * 64 + lane;
    int row = unit >> 4, u = unit & 15;
    int u2 = (u & 1) | (((((u >> 1) & 7) ^ (row & 7))) << 1);
    xrow[i] = row; xcol[i] = u2 << 2;          // f32 element offset in 64-wide slice
  }
  // W staging map (fp16): 1024 units of 16B(8 h); 8 units/row
  int wrow[4], wcol[4];
  #pragma unroll
  for (int i = 0; i < 4; ++i) {
    int unit = i * 256 + w * 64 + lane;
    int row = unit >> 3, u = unit & 7;
    wrow[i] = row; wcol[i] = (u ^ (row & 7)) << 3;
  }

  f32x4 acc[4][4] = {};
  const bool vpath = (wsel == 2);

  for (int kk = 0; kk < 8; ++kk) {
    __syncthreads();                  // all waves done reading previous tiles
    #pragma unroll
    for (int i = 0; i < 8; ++i)
      gl16(xb + (size_t)xrow[i] * 512 + kk * 64 + xcol[i], &xs[(i * 256 + w * 64) * 4]);
    #pragma unroll
    for (int i = 0; i < 4; ++i)
      gl16(wb + (size_t)wrow[i] * 512 + kk * 64 + wcol[i], &wl[(i * 256 + w * 64) * 8]);
    __syncthreads();                  // drains vmcnt(0): tiles ready

    #pragma unroll
    for (int ks = 0; ks < 2; ++ks) {
      half8 a[4], bf[4];
      if (!vpath) {
        #pragma unroll
        for (int mr = 0; mr < 4; ++mr) a[mr]  = ldx32(xs, wm * 64 + mr * 16 + l15, ks * 32 + h * 8);
        #pragma unroll
        for (int nr = 0; nr < 4; ++nr) bf[nr] = ldf64(wl, wn * 64 + nr * 16 + l15, ks * 32 + h * 8);
      } else {
        #pragma unroll
        for (int mr = 0; mr < 4; ++mr) a[mr]  = ldf64(wl, wm * 64 + mr * 16 + l15, ks * 32 + h * 8);
        #pragma unroll
        for (int nr = 0; nr < 4; ++nr) bf[nr] = ldx32(xs, wn * 64 + nr * 16 + l15, ks * 32 + h * 8);
      }
      #pragma unroll
      for (int mr = 0; mr < 4; ++mr)
        #pragma unroll
        for (int nr = 0; nr < 4; ++nr)
          acc[mr][nr] = MFMA(a[mr], bf[nr], acc[mr][nr]);
    }
  }

  if (!vpath) {
    _Float16* dst = (wsel == 0) ? q16 : k16;
    const int m0 = stile * 128 + wm * 64;
    const int n0 = (ntile & 3) * 128 + wn * 64;
    #pragma unroll
    for (int mr = 0; mr < 4; ++mr)
      #pragma unroll
      for (int nr = 0; nr < 4; ++nr)
        #pragma unroll
        for (int r = 0; r < 4; ++r)
          dst[(size_t)(m0 + mr * 16 + h * 4 + r) * 512 + n0 + nr * 16 + l15] =
              (_Float16)acc[mr][nr][r];
  } else {
    const int d0 = (ntile & 3) * 128 + wm * 64;
    const int sg = stile * 128 + wn * 64;
    const int bb = sg >> 13, s0 = sg & 8191;
    _Float16* dst = vT + (size_t)bb * 512 * 8192;
    #pragma unroll
    for (int mr = 0; mr < 4; ++mr)
      #pragma unroll
      for (int nr = 0; nr < 4; ++nr)
        #pragma unroll
        for (int r = 0; r < 4; ++r)
          dst[(size_t)(d0 + mr * 16 + h * 4 + r) * 8192 + s0 + nr * 16 + l15] =
              (_Float16)acc[mr][nr][r];
  }
}

// ================= K2: chunked attention, 4 waves per (b,c), staged k/vT, XCD-chunked =================
__global__ __launch_bounds__(256)
void k2_attn(const _Float16* __restrict__ q16, const _Float16* __restrict__ k16,
             const _Float16* __restrict__ vT, float* __restrict__ out)
{
  __shared__ _Float16 kj[2][128 * 64];   // 2x16KB: S: [128 j][64 e] ; PV: [64 d][128 j]
  __shared__ _Float16 p_lds[64 * 128];   // 16KB, [64 q][128 j], swizzled, wave-local use

  const int id = blockIdx.x;             // 512 blocks = 8 XCDs x 64; contiguous c per XCD
  const int sz = (id & 7) * 64 + (id >> 3);
  const int b = sz >> 7, c = sz & 127;
  const int tid = threadIdx.x, lane = tid & 63, w = tid >> 6;
  const int l15 = lane & 15, h = lane >> 4;
  const int jbase = c * 64 - 64;

  // q rows for this wave -> registers (16 x half8), scale pre-folded into Wq
  const _Float16* qrow = q16 + (size_t)(b * 8192 + c * 64 + w * 16 + l15) * 512;
  half8 qa[16];
  #pragma unroll
  for (int ks = 0; ks < 16; ++ks) qa[ks] = *(const half8*)(qrow + ks * 32 + h * 8);

  const _Float16* kb = k16 + (size_t)b * 8192 * 512;

  // ---- S phase: e-loop, double-buffered k-slices ----
  f32x4 S[8] = {};
  {
    #pragma unroll
    for (int i = 0; i < 4; ++i) {
      int unit = i * 256 + w * 64 + lane;
      int row = unit >> 3, u = unit & 7;
      int sj = jbase + row; if (sj < 0) sj = 0;
      gl16(kb + (size_t)sj * 512 + ((u ^ (row & 7)) << 3), &kj[0][(i * 256 + w * 64) * 8]);
    }
    int cur = 0;
    for (int ee = 0; ee < 8; ++ee) {
      __syncthreads();                 // drain stage(cur); waves done reading cur^1
      if (ee < 7) {
        #pragma unroll
        for (int i = 0; i < 4; ++i) {
          int unit = i * 256 + w * 64 + lane;
          int row = unit >> 3, u = unit & 7;
          int sj = jbase + row; if (sj < 0) sj = 0;
          gl16(kb + (size_t)sj * 512 + (ee + 1) * 64 + ((u ^ (row & 7)) << 3),
               &kj[cur ^ 1][(i * 256 + w * 64) * 8]);
        }
      }
      #pragma unroll
      for (int ks = 0; ks < 2; ++ks) {
        #pragma unroll
        for (int nt = 0; nt < 8; ++nt) {
          half8 bf = ldf64(kj[cur], nt * 16 + l15, ks * 32 + h * 8);
          S[nt] = MFMA(qa[ee * 2 + ks], bf, S[nt]);
        }
      }
      cur ^= 1;
    }
  }

  // ---- masked softmax (row q = h*4+r within this wave's 16 rows) ----
  #pragma unroll
  for (int jt = 0; jt < 8; ++jt) {
    int j = jt * 16 + l15;
    #pragma unroll
    for (int r = 0; r < 4; ++r) {
      int ql = w * 16 + h * 4 + r;
      bool valid = (j < 64 + ql) && ((c > 0) || (j >= 64));
      S[jt][r] = valid ? S[jt][r] : -1e30f;
    }
  }
  #pragma unroll
  for (int r = 0; r < 4; ++r) {
    float mx = -1e30f;
    #pragma unroll
    for (int jt = 0; jt < 8; ++jt) mx = fmaxf(mx, S[jt][r]);
    mx = fmaxf(mx, __shfl_xor(mx, 1));
    mx = fmaxf(mx, __shfl_xor(mx, 2));
    mx = fmaxf(mx, __shfl_xor(mx, 4));
    mx = fmaxf(mx, __shfl_xor(mx, 8));
    float sum = 0.f;
    #pragma unroll
    for (int jt = 0; jt < 8; ++jt) {
      float sv = S[jt][r];
      float pe = (sv > -1e29f) ? __expf(sv - mx) : 0.f;
      S[jt][r] = pe;
      sum += pe;
    }
    sum += __shfl_xor(sum, 1);
    sum += __shfl_xor(sum, 2);
    sum += __shfl_xor(sum, 4);
    sum += __shfl_xor(sum, 8);
    float inv = (sum > 0.f) ? (1.0f / sum) : 0.f;   // fully-masked row -> p = 0
    #pragma unroll
    for (int jt = 0; jt < 8; ++jt) {
      int row = w * 16 + h * 4 + r, col = jt * 16 + l15;
      _Float16 ph = (_Float16)(S[jt][r] * inv);
      *(_Float16*)((char*)p_lds + row * 256 + ((col << 1) ^ ((row & 7) << 4))) = ph;
    }
  }
  // p A-frags (wave-local RAW; compiler inserts lgkmcnt wait)
  half8 pa[4];
  #pragma unroll
  for (int ks = 0; ks < 4; ++ks) {
    int row = w * 16 + l15, colh = ks * 32 + h * 8;
    pa[ks] = *(const half8*)((const char*)p_lds + row * 256 + ((colh << 1) ^ ((row & 7) << 4)));
  }

  // ---- PV phase: d-loop, double-buffered vT-slices [64 d][128 j] ----
  const _Float16* vb = vT + (size_t)b * 512 * 8192;
  float* ob = out + (size_t)(b * 8192 + c * 64 + w * 16) * 512;

  __syncthreads();                     // everyone done with S-phase kj reads
  #pragma unroll
  for (int i = 0; i < 4; ++i) {        // prologue stage dd=0 into buf 0
    int unit = i * 256 + w * 64 + lane;
    int row = unit >> 4, u = unit & 15;
    int u2 = (u & 8) | ((u & 7) ^ (row & 7));
    int js = jbase + u2 * 8; if (js < 0) js = 0;
    gl16(vb + (size_t)row * 8192 + js, &kj[0][(i * 256 + w * 64) * 8]);
  }
  int cur = 0;
  for (int dd = 0; dd < 8; ++dd) {
    __syncthreads();                   // drain stage(cur); waves done reading cur^1
    if (dd < 7) {
      #pragma unroll
      for (int i = 0; i < 4; ++i) {
        int unit = i * 256 + w * 64 + lane;
        int row = unit >> 4, u = unit & 15;
        int u2 = (u & 8) | ((u & 7) ^ (row & 7));
        int js = jbase + u2 * 8; if (js < 0) js = 0;
        gl16(vb + (size_t)((dd + 1) * 64 + row) * 8192 + js, &kj[cur ^ 1][(i * 256 + w * 64) * 8]);
      }
    }
    f32x4 o[4] = {};
    #pragma unroll
    for (int ks = 0; ks < 4; ++ks) {
      #pragma unroll
      for (int nr = 0; nr < 4; ++nr) {
        half8 bf = ldf128(kj[cur], nr * 16 + l15, ks * 32 + h * 8);
        o[nr] = MFMA(pa[ks], bf, o[nr]);
      }
    }
    #pragma unroll
    for (int nr = 0; nr < 4; ++nr)
      #pragma unroll
      for (int r = 0; r < 4; ++r)
        ob[(size_t)(h * 4 + r) * 512 + dd * 64 + nr * 16 + l15] = o[nr][r];
    cur ^= 1;
  }
}

// ================= fallback: round-1 fused kernel (used only if ws too small) =================
__device__ __forceinline__ int swzb(int row, int colByte) {
  return colByte ^ ((row & 7) << 4);
}
__device__ __forceinline__ half8 ldw_frag(const float* __restrict__ W, int row, int e0) {
  const float4* p = reinterpret_cast<const float4*>(W + ((size_t)row << 9) + e0);
  float4 f0 = p[0];
  float4 f1 = p[1];
  half8 v;
  v[0] = (_Float16)f0.x; v[1] = (_Float16)f0.y; v[2] = (_Float16)f0.z; v[3] = (_Float16)f0.w;
  v[4] = (_Float16)f1.x; v[5] = (_Float16)f1.y; v[6] = (_Float16)f1.z; v[7] = (_Float16)f1.w;
  return v;
}
__device__ __forceinline__ half8 ldl_frag(const unsigned short* buf, int row, int col, int strideBytes) {
  int byte = row * strideBytes + swzb(row, col << 1);
  return *reinterpret_cast<const half8*>(reinterpret_cast<const char*>(buf) + byte);
}

__global__ __launch_bounds__(256, 1)
void ep_fused(const float* __restrict__ x, const float* __restrict__ Wq,
              const float* __restrict__ Wk, const float* __restrict__ Wv,
              float* __restrict__ out)
{
  __shared__ unsigned short xs[128 * 512];
  __shared__ unsigned short kv[64 * 128];
  __shared__ unsigned short pq[64 * 128];

  const int bc   = blockIdx.x;
  const int b    = bc >> 7;
  const int c    = bc & 127;
  const int tid  = threadIdx.x;
  const int lane = tid & 63;
  const int w    = tid >> 6;
  const int l15  = lane & 15;
  const int h    = lane >> 4;

  const float* xb = x + (size_t)b * (8192 * 512);
  #pragma unroll
  for (int i = 0; i < 32; ++i) {
    int unit = tid + (i << 8);
    int row  = unit >> 6;
    int e0   = (unit & 63) << 3;
    half8 v;
    if (c == 0 && row < 64) {
      #pragma unroll
      for (int t = 0; t < 8; ++t) v[t] = (_Float16)0.0f;
    } else {
      int s = c * 64 - 64 + row;
      const float4* p = reinterpret_cast<const float4*>(xb + (size_t)s * 512 + e0);
      float4 f0 = p[0], f1 = p[1];
      v[0] = (_Float16)f0.x; v[1] = (_Float16)f0.y; v[2] = (_Float16)f0.z; v[3] = (_Float16)f0.w;
      v[4] = (_Float16)f1.x; v[5] = (_Float16)f1.y; v[6] = (_Float16)f1.z; v[7] = (_Float16)f1.w;
    }
    int byte = (row << 10) + swzb(row, e0 << 1);
    *reinterpret_cast<half8*>(reinterpret_cast<char*>(xs) + byte) = v;
  }
  __syncthreads();

  f32x4 Sacc[8] = {};
  const int d0 = (w << 4) + (h << 2);

  for (int dt = 0; dt < 8; ++dt) {
    const int drow = (dt << 6) + (w << 4) + l15;

    f32x4 qa[4] = {};
    for (int ks = 0; ks < 16; ++ks) {
      half8 a = ldw_frag(Wq, drow, (ks << 5) + (h << 3));
      #pragma unroll
      for (int nt = 0; nt < 4; ++nt) {
        half8 bf = ldl_frag(xs, 64 + (nt << 4) + l15, (ks << 5) + (h << 3), 1024);
        qa[nt] = MFMA(a, bf, qa[nt]);
      }
    }
    #pragma unroll
    for (int nt = 0; nt < 4; ++nt) {
      int q = (nt << 4) + l15;
      half4 hv;
      hv[0] = (_Float16)qa[nt][0]; hv[1] = (_Float16)qa[nt][1];
      hv[2] = (_Float16)qa[nt][2]; hv[3] = (_Float16)qa[nt][3];
      *reinterpret_cast<half4*>(reinterpret_cast<char*>(pq) + q * 128 + swzb(q, d0 << 1)) = hv;
    }

    f32x4 ka[8] = {};
    for (int ks = 0; ks < 16; ++ks) {
      half8 a = ldw_frag(Wk, drow, (ks << 5) + (h << 3));
      #pragma unroll
      for (int nt = 0; nt < 8; ++nt) {
        half8 bf = ldl_frag(xs, (nt << 4) + l15, (ks << 5) + (h << 3), 1024);
        ka[nt] = MFMA(a, bf, ka[nt]);
      }
    }
    #pragma unroll
    for (int nt = 0; nt < 8; ++nt) {
      int j = (nt << 4) + l15;
      half4 hv;
      hv[0] = (_Float16)ka[nt][0]; hv[1] = (_Float16)ka[nt][1];
      hv[2] = (_Float16)ka[nt][2]; hv[3] = (_Float16)ka[nt][3];
      *reinterpret_cast<half4*>(reinterpret_cast<char*>(kv) + j * 128 + swzb(j, d0 << 1)) = hv;
    }
    __syncthreads();

    #pragma unroll
    for (int ksd = 0; ksd < 2; ++ksd) {
      half8 a = ldl_frag(pq, (w << 4) + l15, (ksd << 5) + (h << 3), 128);
      #pragma unroll
      for (int nt = 0; nt < 8; ++nt) {
        half8 bf = ldl_frag(kv, (nt << 4) + l15, (ksd << 5) + (h << 3), 128);
        Sacc[nt] = MFMA(a, bf, Sacc[nt]);
      }
    }
    __syncthreads();
  }

  const float scale = SCALE;
  #pragma unroll
  for (int nt = 0; nt < 8; ++nt) {
    int j = (nt << 4) + l15;
    #pragma unroll
    for (int r = 0; r < 4; ++r) {
      int qrow = (w << 4) + (h << 2) + r;
      bool valid = (j < 64 + qrow) && ((c > 0) || (j >= 64));
      Sacc[nt][r] = valid ? Sacc[nt][r] * scale : -1e30f;
    }
  }
  float inv[4];
  #pragma unroll
  for (int r = 0; r < 4; ++r) {
    float mx = -1e30f;
    #pragma unroll
    for (int nt = 0; nt < 8; ++nt) mx = fmaxf(mx, Sacc[nt][r]);
    mx = fmaxf(mx, __shfl_xor(mx, 1));
    mx = fmaxf(mx, __shfl_xor(mx, 2));
    mx = fmaxf(mx, __shfl_xor(mx, 4));
    mx = fmaxf(mx, __shfl_xor(mx, 8));
    float sum = 0.f;
    #pragma unroll
    for (int nt = 0; nt < 8; ++nt) {
      float sv = Sacc[nt][r];
      float pe = (sv > -1e29f) ? __expf(sv - mx) : 0.f;
      Sacc[nt][r] = pe;
      sum += pe;
    }
    sum += __shfl_xor(sum, 1);
    sum += __shfl_xor(sum, 2);
    sum += __shfl_xor(sum, 4);
    sum += __shfl_xor(sum, 8);
    inv[r] = (sum > 0.f) ? (1.0f / sum) : 0.f;
  }
  #pragma unroll
  for (int nt = 0; nt < 8; ++nt) {
    int j = (nt << 4) + l15;
    #pragma unroll
    for (int r = 0; r < 4; ++r) {
      int qrow = (w << 4) + (h << 2) + r;
      _Float16 ph = (_Float16)(Sacc[nt][r] * inv[r]);
      *reinterpret_cast<_Float16*>(reinterpret_cast<char*>(pq) + qrow * 256 + swzb(qrow, j << 1)) = ph;
    }
  }
  __syncthreads();

  for (int dt = 0; dt < 8; ++dt) {
    const int dcol = (dt << 6) + (w << 4) + l15;

    f32x4 va[8] = {};
    for (int ks = 0; ks < 16; ++ks) {
      half8 bf = ldw_frag(Wv, dcol, (ks << 5) + (h << 3));
      #pragma unroll
      for (int mt = 0; mt < 8; ++mt) {
        half8 a = ldl_frag(xs, (mt << 4) + l15, (ks << 5) + (h << 3), 1024);
        va[mt] = MFMA(a, bf, va[mt]);
      }
    }
    {
      int dl = (w << 4) + l15;
      #pragma unroll
      for (int mt = 0; mt < 8; ++mt) {
        int j0 = (mt << 4) + (h << 2);
        half4 hv;
        hv[0] = (_Float16)va[mt][0]; hv[1] = (_Float16)va[mt][1];
        hv[2] = (_Float16)va[mt][2]; hv[3] = (_Float16)va[mt][3];
        *reinterpret_cast<half4*>(reinterpret_cast<char*>(kv) + dl * 256 + swzb(dl, j0 << 1)) = hv;
      }
    }
    __syncthreads();

    f32x4 oa[4] = {};
    #pragma unroll
    for (int ks = 0; ks < 4; ++ks) {
      half8 a = ldl_frag(pq, (w << 4) + l15, (ks << 5) + (h << 3), 256);
      #pragma unroll
      for (int nt = 0; nt < 4; ++nt) {
        half8 bf = ldl_frag(kv, (nt << 4) + l15, (ks << 5) + (h << 3), 256);
        oa[nt] = MFMA(a, bf, oa[nt]);
      }
    }
    #pragma unroll
    for (int nt = 0; nt < 4; ++nt) {
      int d = (dt << 6) + (nt << 4) + l15;
      #pragma unroll
      for (int r = 0; r < 4; ++r) {
        int qrow = (w << 4) + (h << 2) + r;
        out[((size_t)(b * 8192 + (c << 6) + qrow) << 9) + d] = oa[nt][r];
      }
    }
    __syncthreads();
  }
}

extern "C" void kernel_launch(void* const* d_in, const int* in_sizes, int n_in,
                              void* d_out, int out_size, void* d_ws, size_t ws_size,
                              hipStream_t stream) {
  const float* x  = (const float*)d_in[0];
  const float* Wq = (const float*)d_in[1];
  const float* Wk = (const float*)d_in[2];
  const float* Wv = (const float*)d_in[3];
  float* out = (float*)d_out;
  (void)in_sizes; (void)n_in; (void)out_size;

  if (d_ws != nullptr && ws_size >= WS_NEED) {
    char* ws = (char*)d_ws;
    _Float16* q16 = (_Float16*)(ws + Q16_OFF);
    _Float16* k16 = (_Float16*)(ws + K16_OFF);
    _Float16* vT  = (_Float16*)(ws + VT_OFF);
    _Float16* w16 = (_Float16*)(ws + W16_OFF);

    hipLaunchKernelGGL(k0_cvtW, dim3(384), dim3(256), 0, stream, Wq, Wk, Wv, w16);
    hipLaunchKernelGGL(k1_gemm, dim3(3072), dim3(256), 0, stream, x, w16, q16, k16, vT);
    hipLaunchKernelGGL(k2_attn, dim3(512), dim3(256), 0, stream, q16, k16, vT, out);
  } else {
    hipLaunchKernelGGL(ep_fused, dim3(512), dim3(256), 0, stream, x, Wq, Wk, Wv, out);
  }
}

// Round 5
// 113.384 us; speedup vs baseline: 3.7138x; 1.0835x over previous
//
#include <hip/hip_runtime.h>

#define SCALE 0.044194173824159216f   // 1/sqrt(512)

typedef _Float16 half8 __attribute__((ext_vector_type(8)));
typedef _Float16 half4 __attribute__((ext_vector_type(4)));
typedef float    f32x4 __attribute__((ext_vector_type(4)));

#define MFMA(A, B, Cc) __builtin_amdgcn_mfma_f32_16x16x32_f16((A), (B), (Cc), 0, 0, 0)

// ---------------- ws layout (bytes) ----------------
#define X16_OFF 0ull
#define Q16_OFF 33554432ull
#define K16_OFF 67108864ull
#define VT_OFF  100663296ull
#define W16_OFF 134217728ull    // W_all fp16 [1536][512]: Wq~(scaled), Wk, Wv
#define WS_NEED 135790592ull

typedef __attribute__((address_space(1))) const unsigned int glb_t;
typedef __attribute__((address_space(3))) unsigned int lds_t;

// async global->LDS, 16B per lane; LDS dest = wave-uniform base + lane*16
__device__ __forceinline__ void gl16(const void* g, void* l) {
  __builtin_amdgcn_global_load_lds((glb_t*)g, (lds_t*)l, 16, 0, 0);
}

// swizzled read of a [R][64] fp16 tile (row stride 128B): LDS[row][u16] = glob[row][u16^(row&7)]
__device__ __forceinline__ half8 ldf64(const _Float16* buf, int row, int colh) {
  int byte = row * 128 + (((colh) << 1) ^ ((row & 7) << 4));
  return *(const half8*)((const char*)buf + byte);
}
// swizzled read of a [R][128] fp16 tile (row stride 256B)
__device__ __forceinline__ half8 ldf128(const _Float16* buf, int row, int colh) {
  int byte = row * 256 + (((colh) << 1) ^ ((row & 7) << 4));
  return *(const half8*)((const char*)buf + byte);
}

// ================= K0: fp32 -> fp16 convert (x; W with 1/sqrt(D) folded into Wq) =================
__global__ __launch_bounds__(256)
void k0_cvt(const float* __restrict__ x, const float* __restrict__ Wq,
            const float* __restrict__ Wk, const float* __restrict__ Wv,
            _Float16* __restrict__ x16, _Float16* __restrict__ w16)
{
  const long long NX = 16777216LL;   // 4*8192*512
  long long base = ((long long)blockIdx.x * 256 + threadIdx.x) * 8;
  const float* src;
  _Float16* dst;
  float sc = 1.0f;
  if (base < NX) {
    src = x + base; dst = x16 + base;
  } else {
    long long o = base - NX;             // 0 .. 786431
    int ws = (int)(o >> 18);
    long long oo = o & 262143LL;
    src = (ws == 0 ? Wq : (ws == 1 ? Wk : Wv)) + oo;
    dst = w16 + o;
    if (ws == 0) sc = SCALE;
  }
  const float4* p = (const float4*)src;
  float4 f0 = p[0], f1 = p[1];
  half8 v;
  v[0] = (_Float16)(f0.x * sc); v[1] = (_Float16)(f0.y * sc);
  v[2] = (_Float16)(f0.z * sc); v[3] = (_Float16)(f0.w * sc);
  v[4] = (_Float16)(f1.x * sc); v[5] = (_Float16)(f1.y * sc);
  v[6] = (_Float16)(f1.z * sc); v[7] = (_Float16)(f1.w * sc);
  *(half8*)dst = v;
}

// ================= K1: 128x128 GEMM, fp16 staged, double-buffered, counted vmcnt =================
// C = x16[32768,512] @ W_all[1536,512]^T ; ntile 0..3 -> q, 4..7 -> k, 8..11 -> vT(transposed)
__global__ __launch_bounds__(256)
void k1_gemm(const _Float16* __restrict__ x16, const _Float16* __restrict__ w16,
             _Float16* __restrict__ q16, _Float16* __restrict__ k16,
             _Float16* __restrict__ vT)
{
  __shared__ _Float16 xs[2][8192];   // 2x16KB, [128 s][64 e], src-swizzled
  __shared__ _Float16 wl[2][8192];   // 2x16KB, [128 n][64 e], src-swizzled

  // bijective XCD swizzle: 3072 blocks = 8 XCDs x 384; each XCD gets a contiguous
  // stile chunk (32 stiles x 12 ntiles) -> every x-tile fetched on exactly 1 XCD.
  const int id  = blockIdx.x;
  const int swz = (id & 7) * 384 + (id >> 3);
  const int ntile = swz % 12;
  const int stile = swz / 12;
  const int wsel  = ntile >> 2;
  const int tid = threadIdx.x, lane = tid & 63, w = tid >> 6;
  const int l15 = lane & 15, h = lane >> 4;
  const int wm = w >> 1, wn = w & 1;

  const _Float16* xb = x16 + (size_t)stile * 128 * 512;
  const _Float16* wb = w16 + (size_t)ntile * 128 * 512;

  // staging map: unit = i*256 + w*64 + lane ; row = unit>>3 ; src col-unit = u ^ (row&7)
  int rowi[4], coli[4];
  #pragma unroll
  for (int i = 0; i < 4; ++i) {
    int unit = i * 256 + w * 64 + lane;
    int row = unit >> 3, u = unit & 7;
    rowi[i] = row;
    coli[i] = (u ^ (row & 7)) << 3;
  }

  f32x4 acc[4][4] = {};
  const bool vpath = (wsel == 2);

  // prologue: stage kk=0 into buf 0  (8 gl16 per wave)
  #pragma unroll
  for (int i = 0; i < 4; ++i) {
    int ub = i * 256 + w * 64;
    gl16(xb + (size_t)rowi[i] * 512 + coli[i], &xs[0][ub * 8]);
    gl16(wb + (size_t)rowi[i] * 512 + coli[i], &wl[0][ub * 8]);
  }

  for (int kk = 0; kk < 8; ++kk) {
    const int cur = kk & 1;
    if (kk < 7) {
      const int nxt = cur ^ 1;
      #pragma unroll
      for (int i = 0; i < 4; ++i) {
        int ub = i * 256 + w * 64;
        gl16(xb + (size_t)rowi[i] * 512 + (kk + 1) * 64 + coli[i], &xs[nxt][ub * 8]);
        gl16(wb + (size_t)rowi[i] * 512 + (kk + 1) * 64 + coli[i], &wl[nxt][ub * 8]);
      }
      asm volatile("s_waitcnt vmcnt(8)" ::: "memory");   // kk's 8 loads done; kk+1's stay in flight
    } else {
      asm volatile("s_waitcnt vmcnt(0)" ::: "memory");
    }
    __builtin_amdgcn_s_barrier();
    __builtin_amdgcn_sched_barrier(0);

    #pragma unroll
    for (int ks = 0; ks < 2; ++ks) {
      half8 a[4], bf[4];
      if (!vpath) {
        #pragma unroll
        for (int mr = 0; mr < 4; ++mr) a[mr]  = ldf64(xs[cur], wm * 64 + mr * 16 + l15, ks * 32 + h * 8);
        #pragma unroll
        for (int nr = 0; nr < 4; ++nr) bf[nr] = ldf64(wl[cur], wn * 64 + nr * 16 + l15, ks * 32 + h * 8);
      } else {
        #pragma unroll
        for (int mr = 0; mr < 4; ++mr) a[mr]  = ldf64(wl[cur], wm * 64 + mr * 16 + l15, ks * 32 + h * 8);
        #pragma unroll
        for (int nr = 0; nr < 4; ++nr) bf[nr] = ldf64(xs[cur], wn * 64 + nr * 16 + l15, ks * 32 + h * 8);
      }
      #pragma unroll
      for (int mr = 0; mr < 4; ++mr)
        #pragma unroll
        for (int nr = 0; nr < 4; ++nr)
          acc[mr][nr] = MFMA(a[mr], bf[nr], acc[mr][nr]);
    }

    __builtin_amdgcn_sched_barrier(0);   // keep ds_reads above the reuse barrier
    __builtin_amdgcn_s_barrier();        // all waves done reading buf cur before it's restaged
  }

  if (!vpath) {
    _Float16* dst = (wsel == 0) ? q16 : k16;
    const int m0 = stile * 128 + wm * 64;
    const int n0 = (ntile & 3) * 128 + wn * 64;
    #pragma unroll
    for (int mr = 0; mr < 4; ++mr)
      #pragma unroll
      for (int nr = 0; nr < 4; ++nr)
        #pragma unroll
        for (int r = 0; r < 4; ++r)
          dst[(size_t)(m0 + mr * 16 + h * 4 + r) * 512 + n0 + nr * 16 + l15] =
              (_Float16)acc[mr][nr][r];
  } else {
    const int d0 = (ntile & 3) * 128 + wm * 64;
    const int sg = stile * 128 + wn * 64;
    const int bb = sg >> 13, s0 = sg & 8191;
    _Float16* dst = vT + (size_t)bb * 512 * 8192;
    #pragma unroll
    for (int mr = 0; mr < 4; ++mr)
      #pragma unroll
      for (int nr = 0; nr < 4; ++nr)
        #pragma unroll
        for (int r = 0; r < 4; ++r)
          dst[(size_t)(d0 + mr * 16 + h * 4 + r) * 8192 + s0 + nr * 16 + l15] =
              (_Float16)acc[mr][nr][r];
  }
}

// ================= K2: chunked attention, 4 waves per (b,c), staged k/vT, XCD-chunked =================
__global__ __launch_bounds__(256)
void k2_attn(const _Float16* __restrict__ q16, const _Float16* __restrict__ k16,
             const _Float16* __restrict__ vT, float* __restrict__ out)
{
  __shared__ _Float16 kj[2][128 * 64];   // 2x16KB: S: [128 j][64 e] ; PV: [64 d][128 j]
  __shared__ _Float16 p_lds[64 * 128];   // 16KB, [64 q][128 j], swizzled, wave-local use

  const int id = blockIdx.x;             // 512 blocks = 8 XCDs x 64; contiguous c per XCD
  const int sz = (id & 7) * 64 + (id >> 3);
  const int b = sz >> 7, c = sz & 127;
  const int tid = threadIdx.x, lane = tid & 63, w = tid >> 6;
  const int l15 = lane & 15, h = lane >> 4;
  const int jbase = c * 64 - 64;

  const _Float16* qrow = q16 + (size_t)(b * 8192 + c * 64 + w * 16 + l15) * 512;
  half8 qa[16];
  #pragma unroll
  for (int ks = 0; ks < 16; ++ks) qa[ks] = *(const half8*)(qrow + ks * 32 + h * 8);

  const _Float16* kb = k16 + (size_t)b * 8192 * 512;

  // ---- S phase: e-loop, double-buffered k-slices ----
  f32x4 S[8] = {};
  {
    #pragma unroll
    for (int i = 0; i < 4; ++i) {
      int unit = i * 256 + w * 64 + lane;
      int row = unit >> 3, u = unit & 7;
      int sj = jbase + row; if (sj < 0) sj = 0;
      gl16(kb + (size_t)sj * 512 + ((u ^ (row & 7)) << 3), &kj[0][(i * 256 + w * 64) * 8]);
    }
    int cur = 0;
    for (int ee = 0; ee < 8; ++ee) {
      __syncthreads();                 // drain stage(cur); waves done reading cur^1
      if (ee < 7) {
        #pragma unroll
        for (int i = 0; i < 4; ++i) {
          int unit = i * 256 + w * 64 + lane;
          int row = unit >> 3, u = unit & 7;
          int sj = jbase + row; if (sj < 0) sj = 0;
          gl16(kb + (size_t)sj * 512 + (ee + 1) * 64 + ((u ^ (row & 7)) << 3),
               &kj[cur ^ 1][(i * 256 + w * 64) * 8]);
        }
      }
      #pragma unroll
      for (int ks = 0; ks < 2; ++ks) {
        #pragma unroll
        for (int nt = 0; nt < 8; ++nt) {
          half8 bf = ldf64(kj[cur], nt * 16 + l15, ks * 32 + h * 8);
          S[nt] = MFMA(qa[ee * 2 + ks], bf, S[nt]);
        }
      }
      cur ^= 1;
    }
  }

  // ---- masked softmax ----
  #pragma unroll
  for (int jt = 0; jt < 8; ++jt) {
    int j = jt * 16 + l15;
    #pragma unroll
    for (int r = 0; r < 4; ++r) {
      int ql = w * 16 + h * 4 + r;
      bool valid = (j < 64 + ql) && ((c > 0) || (j >= 64));
      S[jt][r] = valid ? S[jt][r] : -1e30f;
    }
  }
  #pragma unroll
  for (int r = 0; r < 4; ++r) {
    float mx = -1e30f;
    #pragma unroll
    for (int jt = 0; jt < 8; ++jt) mx = fmaxf(mx, S[jt][r]);
    mx = fmaxf(mx, __shfl_xor(mx, 1));
    mx = fmaxf(mx, __shfl_xor(mx, 2));
    mx = fmaxf(mx, __shfl_xor(mx, 4));
    mx = fmaxf(mx, __shfl_xor(mx, 8));
    float sum = 0.f;
    #pragma unroll
    for (int jt = 0; jt < 8; ++jt) {
      float sv = S[jt][r];
      float pe = (sv > -1e29f) ? __expf(sv - mx) : 0.f;
      S[jt][r] = pe;
      sum += pe;
    }
    sum += __shfl_xor(sum, 1);
    sum += __shfl_xor(sum, 2);
    sum += __shfl_xor(sum, 4);
    sum += __shfl_xor(sum, 8);
    float inv = (sum > 0.f) ? (1.0f / sum) : 0.f;   // fully-masked row -> p = 0
    #pragma unroll
    for (int jt = 0; jt < 8; ++jt) {
      int row = w * 16 + h * 4 + r, col = jt * 16 + l15;
      _Float16 ph = (_Float16)(S[jt][r] * inv);
      *(_Float16*)((char*)p_lds + row * 256 + ((col << 1) ^ ((row & 7) << 4))) = ph;
    }
  }
  half8 pa[4];
  #pragma unroll
  for (int ks = 0; ks < 4; ++ks) {
    int row = w * 16 + l15, colh = ks * 32 + h * 8;
    pa[ks] = *(const half8*)((const char*)p_lds + row * 256 + ((colh << 1) ^ ((row & 7) << 4)));
  }

  // ---- PV phase: d-loop, double-buffered vT-slices [64 d][128 j] ----
  const _Float16* vb = vT + (size_t)b * 512 * 8192;
  float* ob = out + (size_t)(b * 8192 + c * 64 + w * 16) * 512;

  __syncthreads();
  #pragma unroll
  for (int i = 0; i < 4; ++i) {
    int unit = i * 256 + w * 64 + lane;
    int row = unit >> 4, u = unit & 15;
    int u2 = (u & 8) | ((u & 7) ^ (row & 7));
    int js = jbase + u2 * 8; if (js < 0) js = 0;
    gl16(vb + (size_t)row * 8192 + js, &kj[0][(i * 256 + w * 64) * 8]);
  }
  int cur = 0;
  for (int dd = 0; dd < 8; ++dd) {
    __syncthreads();
    if (dd < 7) {
      #pragma unroll
      for (int i = 0; i < 4; ++i) {
        int unit = i * 256 + w * 64 + lane;
        int row = unit >> 4, u = unit & 15;
        int u2 = (u & 8) | ((u & 7) ^ (row & 7));
        int js = jbase + u2 * 8; if (js < 0) js = 0;
        gl16(vb + (size_t)((dd + 1) * 64 + row) * 8192 + js, &kj[cur ^ 1][(i * 256 + w * 64) * 8]);
      }
    }
    f32x4 o[4] = {};
    #pragma unroll
    for (int ks = 0; ks < 4; ++ks) {
      #pragma unroll
      for (int nr = 0; nr < 4; ++nr) {
        half8 bf = ldf128(kj[cur], nr * 16 + l15, ks * 32 + h * 8);
        o[nr] = MFMA(pa[ks], bf, o[nr]);
      }
    }
    #pragma unroll
    for (int nr = 0; nr < 4; ++nr)
      #pragma unroll
      for (int r = 0; r < 4; ++r)
        ob[(size_t)(h * 4 + r) * 512 + dd * 64 + nr * 16 + l15] = o[nr][r];
    cur ^= 1;
  }
}

// ================= fallback: round-1 fused kernel (used only if ws too small) =================
__device__ __forceinline__ int swzb(int row, int colByte) {
  return colByte ^ ((row & 7) << 4);
}
__device__ __forceinline__ half8 ldw_frag(const float* __restrict__ W, int row, int e0) {
  const float4* p = reinterpret_cast<const float4*>(W + ((size_t)row << 9) + e0);
  float4 f0 = p[0];
  float4 f1 = p[1];
  half8 v;
  v[0] = (_Float16)f0.x; v[1] = (_Float16)f0.y; v[2] = (_Float16)f0.z; v[3] = (_Float16)f0.w;
  v[4] = (_Float16)f1.x; v[5] = (_Float16)f1.y; v[6] = (_Float16)f1.z; v[7] = (_Float16)f1.w;
  return v;
}
__device__ __forceinline__ half8 ldl_frag(const unsigned short* buf, int row, int col, int strideBytes) {
  int byte = row * strideBytes + swzb(row, col << 1);
  return *reinterpret_cast<const half8*>(reinterpret_cast<const char*>(buf) + byte);
}

__global__ __launch_bounds__(256, 1)
void ep_fused(const float* __restrict__ x, const float* __restrict__ Wq,
              const float* __restrict__ Wk, const float* __restrict__ Wv,
              float* __restrict__ out)
{
  __shared__ unsigned short xs[128 * 512];
  __shared__ unsigned short kv[64 * 128];
  __shared__ unsigned short pq[64 * 128];

  const int bc   = blockIdx.x;
  const int b    = bc >> 7;
  const int c    = bc & 127;
  const int tid  = threadIdx.x;
  const int lane = tid & 63;
  const int w    = tid >> 6;
  const int l15  = lane & 15;
  const int h    = lane >> 4;

  const float* xb = x + (size_t)b * (8192 * 512);
  #pragma unroll
  for (int i = 0; i < 32; ++i) {
    int unit = tid + (i << 8);
    int row  = unit >> 6;
    int e0   = (unit & 63) << 3;
    half8 v;
    if (c == 0 && row < 64) {
      #pragma unroll
      for (int t = 0; t < 8; ++t) v[t] = (_Float16)0.0f;
    } else {
      int s = c * 64 - 64 + row;
      const float4* p = reinterpret_cast<const float4*>(xb + (size_t)s * 512 + e0);
      float4 f0 = p[0], f1 = p[1];
      v[0] = (_Float16)f0.x; v[1] = (_Float16)f0.y; v[2] = (_Float16)f0.z; v[3] = (_Float16)f0.w;
      v[4] = (_Float16)f1.x; v[5] = (_Float16)f1.y; v[6] = (_Float16)f1.z; v[7] = (_Float16)f1.w;
    }
    int byte = (row << 10) + swzb(row, e0 << 1);
    *reinterpret_cast<half8*>(reinterpret_cast<char*>(xs) + byte) = v;
  }
  __syncthreads();

  f32x4 Sacc[8] = {};
  const int d0 = (w << 4) + (h << 2);

  for (int dt = 0; dt < 8; ++dt) {
    const int drow = (dt << 6) + (w << 4) + l15;

    f32x4 qa[4] = {};
    for (int ks = 0; ks < 16; ++ks) {
      half8 a = ldw_frag(Wq, drow, (ks << 5) + (h << 3));
      #pragma unroll
      for (int nt = 0; nt < 4; ++nt) {
        half8 bf = ldl_frag(xs, 64 + (nt << 4) + l15, (ks << 5) + (h << 3), 1024);
        qa[nt] = MFMA(a, bf, qa[nt]);
      }
    }
    #pragma unroll
    for (int nt = 0; nt < 4; ++nt) {
      int q = (nt << 4) + l15;
      half4 hv;
      hv[0] = (_Float16)qa[nt][0]; hv[1] = (_Float16)qa[nt][1];
      hv[2] = (_Float16)qa[nt][2]; hv[3] = (_Float16)qa[nt][3];
      *reinterpret_cast<half4*>(reinterpret_cast<char*>(pq) + q * 128 + swzb(q, d0 << 1)) = hv;
    }

    f32x4 ka[8] = {};
    for (int ks = 0; ks < 16; ++ks) {
      half8 a = ldw_frag(Wk, drow, (ks << 5) + (h << 3));
      #pragma unroll
      for (int nt = 0; nt < 8; ++nt) {
        half8 bf = ldl_frag(xs, (nt << 4) + l15, (ks << 5) + (h << 3), 1024);
        ka[nt] = MFMA(a, bf, ka[nt]);
      }
    }
    #pragma unroll
    for (int nt = 0; nt < 8; ++nt) {
      int j = (nt << 4) + l15;
      half4 hv;
      hv[0] = (_Float16)ka[nt][0]; hv[1] = (_Float16)ka[nt][1];
      hv[2] = (_Float16)ka[nt][2]; hv[3] = (_Float16)ka[nt][3];
      *reinterpret_cast<half4*>(reinterpret_cast<char*>(kv) + j * 128 + swzb(j, d0 << 1)) = hv;
    }
    __syncthreads();

    #pragma unroll
    for (int ksd = 0; ksd < 2; ++ksd) {
      half8 a = ldl_frag(pq, (w << 4) + l15, (ksd << 5) + (h << 3), 128);
      #pragma unroll
      for (int nt = 0; nt < 8; ++nt) {
        half8 bf = ldl_frag(kv, (nt << 4) + l15, (ksd << 5) + (h << 3), 128);
        Sacc[nt] = MFMA(a, bf, Sacc[nt]);
      }
    }
    __syncthreads();
  }

  const float scale = SCALE;
  #pragma unroll
  for (int nt = 0; nt < 8; ++nt) {
    int j = (nt << 4) + l15;
    #pragma unroll
    for (int r = 0; r < 4; ++r) {
      int qrow = (w << 4) + (h << 2) + r;
      bool valid = (j < 64 + qrow) && ((c > 0) || (j >= 64));
      Sacc[nt][r] = valid ? Sacc[nt][r] * scale : -1e30f;
    }
  }
  float inv[4];
  #pragma unroll
  for (int r = 0; r < 4; ++r) {
    float mx = -1e30f;
    #pragma unroll
    for (int nt = 0; nt < 8; ++nt) mx = fmaxf(mx, Sacc[nt][r]);
    mx = fmaxf(mx, __shfl_xor(mx, 1));
    mx = fmaxf(mx, __shfl_xor(mx, 2));
    mx = fmaxf(mx, __shfl_xor(mx, 4));
    mx = fmaxf(mx, __shfl_xor(mx, 8));
    float sum = 0.f;
    #pragma unroll
    for (int nt = 0; nt < 8; ++nt) {
      float sv = Sacc[nt][r];
      float pe = (sv > -1e29f) ? __expf(sv - mx) : 0.f;
      Sacc[nt][r] = pe;
      sum += pe;
    }
    sum += __shfl_xor(sum, 1);
    sum += __shfl_xor(sum, 2);
    sum += __shfl_xor(sum, 4);
    sum += __shfl_xor(sum, 8);
    inv[r] = (sum > 0.f) ? (1.0f / sum) : 0.f;
  }
  #pragma unroll
  for (int nt = 0; nt < 8; ++nt) {
    int j = (nt << 4) + l15;
    #pragma unroll
    for (int r = 0; r < 4; ++r) {
      int qrow = (w << 4) + (h << 2) + r;
      _Float16 ph = (_Float16)(Sacc[nt][r] * inv[r]);
      *reinterpret_cast<_Float16*>(reinterpret_cast<char*>(pq) + qrow * 256 + swzb(qrow, j << 1)) = ph;
    }
  }
  __syncthreads();

  for (int dt = 0; dt < 8; ++dt) {
    const int dcol = (dt << 6) + (w << 4) + l15;

    f32x4 va[8] = {};
    for (int ks = 0; ks < 16; ++ks) {
      half8 bf = ldw_frag(Wv, dcol, (ks << 5) + (h << 3));
      #pragma unroll
      for (int mt = 0; mt < 8; ++mt) {
        half8 a = ldl_frag(xs, (mt << 4) + l15, (ks << 5) + (h << 3), 1024);
        va[mt] = MFMA(a, bf, va[mt]);
      }
    }
    {
      int dl = (w << 4) + l15;
      #pragma unroll
      for (int mt = 0; mt < 8; ++mt) {
        int j0 = (mt << 4) + (h << 2);
        half4 hv;
        hv[0] = (_Float16)va[mt][0]; hv[1] = (_Float16)va[mt][1];
        hv[2] = (_Float16)va[mt][2]; hv[3] = (_Float16)va[mt][3];
        *reinterpret_cast<half4*>(reinterpret_cast<char*>(kv) + dl * 256 + swzb(dl, j0 << 1)) = hv;
      }
    }
    __syncthreads();

    f32x4 oa[4] = {};
    #pragma unroll
    for (int ks = 0; ks < 4; ++ks) {
      half8 a = ldl_frag(pq, (w << 4) + l15, (ks << 5) + (h << 3), 256);
      #pragma unroll
      for (int nt = 0; nt < 4; ++nt) {
        half8 bf = ldl_frag(kv, (nt << 4) + l15, (ks << 5) + (h << 3), 256);
        oa[nt] = MFMA(a, bf, oa[nt]);
      }
    }
    #pragma unroll
    for (int nt = 0; nt < 4; ++nt) {
      int d = (dt << 6) + (nt << 4) + l15;
      #pragma unroll
      for (int r = 0; r < 4; ++r) {
        int qrow = (w << 4) + (h << 2) + r;
        out[((size_t)(b * 8192 + (c << 6) + qrow) << 9) + d] = oa[nt][r];
      }
    }
    __syncthreads();
  }
}

extern "C" void kernel_launch(void* const* d_in, const int* in_sizes, int n_in,
                              void* d_out, int out_size, void* d_ws, size_t ws_size,
                              hipStream_t stream) {
  const float* x  = (const float*)d_in[0];
  const float* Wq = (const float*)d_in[1];
  const float* Wk = (const float*)d_in[2];
  const float* Wv = (const float*)d_in[3];
  float* out = (float*)d_out;
  (void)in_sizes; (void)n_in; (void)out_size;

  if (d_ws != nullptr && ws_size >= WS_NEED) {
    char* ws = (char*)d_ws;
    _Float16* x16 = (_Float16*)(ws + X16_OFF);
    _Float16* q16 = (_Float16*)(ws + Q16_OFF);
    _Float16* k16 = (_Float16*)(ws + K16_OFF);
    _Float16* vT  = (_Float16*)(ws + VT_OFF);
    _Float16* w16 = (_Float16*)(ws + W16_OFF);

    hipLaunchKernelGGL(k0_cvt, dim3(8576), dim3(256), 0, stream, x, Wq, Wk, Wv, x16, w16);
    hipLaunchKernelGGL(k1_gemm, dim3(3072), dim3(256), 0, stream, x16, w16, q16, k16, vT);
    hipLaunchKernelGGL(k2_attn, dim3(512), dim3(256), 0, stream, q16, k16, vT, out);
  } else {
    hipLaunchKernelGGL(ep_fused, dim3(512), dim3(256), 0, stream, x, Wq, Wk, Wv, out);
  }
}